// Round 6
// baseline (1143.325 us; speedup 1.0000x reference)
//
#include <hip/hip_runtime.h>
#include <stdint.h>

typedef unsigned short u16;
typedef __attribute__((ext_vector_type(4))) float f32x4;
typedef __attribute__((ext_vector_type(8))) short s16x8;
typedef __attribute__((ext_vector_type(4))) u16 u16x4;

__device__ __forceinline__ u16 f2bf(float x) {
  union { float f; uint32_t u; } v; v.f = x;
  uint32_t r = v.u + 0x7FFFu + ((v.u >> 16) & 1u);
  return (u16)(r >> 16);
}
__device__ __forceinline__ float bf2f(u16 b) {
  union { uint32_t u; float f; } v; v.u = ((uint32_t)b) << 16;
  return v.f;
}

__device__ __forceinline__ void gload16(const void* g, const void* l) {
  __builtin_amdgcn_global_load_lds((const __attribute__((address_space(1))) void*)g,
                                   (__attribute__((address_space(3))) void*)l,
                                   16, 0, 0);
}

__global__ void fill_k(float* out, int n, float v) {
  for (int i = blockIdx.x * blockDim.x + threadIdx.x; i < n; i += gridDim.x * blockDim.x)
    out[i] = v;
}

// ---------------- fp32 -> bf16 convert (vectorized) ----------------
__global__ void cvt_k(const float* __restrict__ in, u16* __restrict__ out, int n4) {
  int i = blockIdx.x * blockDim.x + threadIdx.x;
  if (i >= n4) return;
  f32x4 v = ((const f32x4*)in)[i];
  u16x4 o;
  o.x = f2bf(v.x); o.y = f2bf(v.y); o.z = f2bf(v.z); o.w = f2bf(v.w);
  ((u16x4*)out)[i] = o;
}

// ---------------- fp32 -> bf16 hi+lo split ----------------
__global__ void cvt2_k(const float* __restrict__ in, u16* __restrict__ hi,
                       u16* __restrict__ lo, int n4) {
  int i = blockIdx.x * blockDim.x + threadIdx.x;
  if (i >= n4) return;
  f32x4 v = ((const f32x4*)in)[i];
  u16x4 h, l;
#pragma unroll
  for (int j = 0; j < 4; ++j) {
    u16 hb = f2bf(v[j]);
    h[j] = hb;
    l[j] = f2bf(v[j] - bf2f(hb));
  }
  ((u16x4*)hi)[i] = h;
  ((u16x4*)lo)[i] = l;
}

// ------------- fp32 [2048][2048] -> bf16 transposed -------------
__global__ void cvtT_k(const float* __restrict__ in, u16* __restrict__ out) {
  __shared__ float t[32][33];
  int tx = threadIdx.x, ty = threadIdx.y;
  int c = blockIdx.x * 32 + tx;
#pragma unroll
  for (int j = 0; j < 4; ++j) {
    int r = blockIdx.y * 32 + ty + j * 8;
    t[ty + j * 8][tx] = in[(size_t)r * 2048 + c];
  }
  __syncthreads();
  int c2 = blockIdx.y * 32 + tx;
#pragma unroll
  for (int j = 0; j < 4; ++j) {
    int r2 = blockIdx.x * 32 + ty + j * 8;
    out[(size_t)r2 * 2048 + c2] = f2bf(t[tx][ty + j * 8]);
  }
}

// ------------- per-head V transpose: qkv[:,4096+h*128+dh] -> Vt[bh][dh][s] -------------
__global__ void vtrans_k(const u16* __restrict__ qkv, u16* __restrict__ Vt) {
  __shared__ u16 t[32][34];
  int bh = blockIdx.z; int b = bh >> 4, h = bh & 15;
  int tx = threadIdx.x, ty = threadIdx.y;
  int dh = blockIdx.x * 32 + tx;
#pragma unroll
  for (int j = 0; j < 4; ++j) {
    int s = blockIdx.y * 32 + ty + j * 8;
    t[ty + j * 8][tx] = qkv[(size_t)(b * 2048 + s) * 6144 + 4096 + h * 128 + dh];
  }
  __syncthreads();
  int s2 = blockIdx.y * 32 + tx;
#pragma unroll
  for (int j = 0; j < 4; ++j) {
    int dh2 = blockIdx.x * 32 + ty + j * 8;
    Vt[(size_t)(bh * 128 + dh2) * 2048 + s2] = t[tx][ty + j * 8];
  }
}

// ------------- bf16 GEMM: C = sum_p A_p[M][K] * B_p[N][K]^T  (split-precision passes) ----
// OUTMODE: 0 = fp32, 1 = bf16, 2 = bf16 hi+lo pair (C, C2)
template <typename CT, int OUTMODE, int NP>
__global__ __launch_bounds__(256) void btgemm_k(const u16* __restrict__ A0,
                                                const u16* __restrict__ B0,
                                                const u16* __restrict__ A1,
                                                const u16* __restrict__ B1,
                                                CT* __restrict__ C,
                                                u16* __restrict__ C2,
                                                int M, int N, int K) {
  __shared__ u16 As[128 * 64];
  __shared__ u16 Bs[128 * 64];
  int nnt = N >> 7;
  int bid = blockIdx.x;
  int nwg = gridDim.x;
  if ((nwg & 7) == 0) { int q = nwg >> 3; bid = (bid & 7) * q + (bid >> 3); }  // XCD swizzle
  int mt = bid / nnt, nt = bid - mt * nnt;
  int tid = threadIdx.x, wave = tid >> 6, lane = tid & 63;
  int l15 = lane & 15, l4 = lane >> 4;
  int wr = wave >> 1, wc = wave & 1;
  int sr = lane >> 3, sc = lane & 7;
  int gsl = (sc ^ sr) * 8;  // pre-swizzled source slot (elements)

  const u16* Alist[2] = {A0, A1};
  const u16* Blist[2] = {B0, B1};
  size_t aoff = (size_t)(mt * 128 + wave * 32 + sr) * K + gsl;
  size_t boff = (size_t)(nt * 128 + wave * 32 + sr) * K + gsl;
  u16* Asw = As + wave * 32 * 64;
  u16* Bsw = Bs + wave * 32 * 64;

  f32x4 acc[4][4];
#pragma unroll
  for (int i = 0; i < 4; ++i)
#pragma unroll
    for (int j = 0; j < 4; ++j) acc[i][j] = f32x4{0.f, 0.f, 0.f, 0.f};

#pragma unroll
  for (int p = 0; p < NP; ++p) {
    const u16* Ag = Alist[p] + aoff;
    const u16* Bg = Blist[p] + boff;
    for (int kt = 0; kt < K; kt += 64) {
#pragma unroll
      for (int i = 0; i < 4; ++i) {
        gload16(Ag + kt + i * 8 * K, Asw + i * 512);
        gload16(Bg + kt + i * 8 * K, Bsw + i * 512);
      }
      __syncthreads();
#pragma unroll
      for (int kk = 0; kk < 2; ++kk) {
        s16x8 af[4], bfr[4];
#pragma unroll
        for (int mf = 0; mf < 4; ++mf) {
          int row = wr * 64 + mf * 16 + l15;
          int sl = ((kk * 4 + l4) ^ (row & 7)) * 8;
          af[mf] = *(const s16x8*)(As + row * 64 + sl);
        }
#pragma unroll
        for (int nf = 0; nf < 4; ++nf) {
          int row = wc * 64 + nf * 16 + l15;
          int sl = ((kk * 4 + l4) ^ (row & 7)) * 8;
          bfr[nf] = *(const s16x8*)(Bs + row * 64 + sl);
        }
#pragma unroll
        for (int mf = 0; mf < 4; ++mf)
#pragma unroll
          for (int nf = 0; nf < 4; ++nf)
            acc[mf][nf] = __builtin_amdgcn_mfma_f32_16x16x32_bf16(af[mf], bfr[nf], acc[mf][nf], 0, 0, 0);
      }
      __syncthreads();
    }
  }

  int crow = mt * 128 + wr * 64 + l4 * 4;
  int ccol = nt * 128 + wc * 64 + l15;
#pragma unroll
  for (int mf = 0; mf < 4; ++mf)
#pragma unroll
    for (int nf = 0; nf < 4; ++nf)
#pragma unroll
      for (int r = 0; r < 4; ++r) {
        size_t idx = (size_t)(crow + mf * 16 + r) * N + (ccol + nf * 16);
        float v = acc[mf][nf][r];
        if constexpr (OUTMODE == 0) {
          C[idx] = v;
        } else if constexpr (OUTMODE == 1) {
          C[idx] = f2bf(v);
        } else {
          u16 hb = f2bf(v);
          C[idx] = hb;
          C2[idx] = f2bf(v - bf2f(hb));
        }
      }
}

// ------------- MFMA flash attention v4: barrier-free, K/V fragments direct from L2 ------
// qkv: [8192][6144] bf16 token-major. Vt: [64][128][2048] bf16. outl: [8192][2048] bf16.
// Grid 1024 1-D; XCD swizzle pins all 16 q-blocks of one (b,h) to one XCD's L2.
__global__ __launch_bounds__(256, 3) void attn4_k(const u16* __restrict__ qkv,
                                                  const u16* __restrict__ Vt,
                                                  u16* __restrict__ outl) {
  __shared__ u16 Ps[4][32][72];  // per-wave P tile (only LDS use)

  int bid = blockIdx.x;
  int bid2 = (bid & 7) * 128 + (bid >> 3);  // bijective XCD swizzle (nwg=1024)
  int bh = bid2 >> 4, qb = bid2 & 15;
  int b = bh >> 4, h = bh & 15;
  int tid = threadIdx.x, wave = tid >> 6, lane = tid & 63;
  int l15 = lane & 15, l4 = lane >> 4;
  int q0 = qb * 128 + wave * 32;
  const float ksc = 0.12751743f;  // log2(e)/sqrt(128)

  const u16* Kb = qkv + (size_t)b * 2048 * 6144 + 2048 + h * 128;  // [kv][*] stride 6144
  const u16* Vb = Vt + (size_t)bh * 128 * 2048;                    // [dh][kv] stride 2048

  s16x8 qf[2][4];
#pragma unroll
  for (int mf = 0; mf < 2; ++mf)
#pragma unroll
    for (int kf = 0; kf < 4; ++kf)
      qf[mf][kf] = *(const s16x8*)(qkv + (size_t)(b * 2048 + q0 + mf * 16 + l15) * 6144 +
                                   h * 128 + kf * 32 + l4 * 8);

  f32x4 po[2][8];
  float mrun[2][4], lrun[2][4];
#pragma unroll
  for (int mf = 0; mf < 2; ++mf) {
#pragma unroll
    for (int n2 = 0; n2 < 8; ++n2) po[mf][n2] = f32x4{0.f, 0.f, 0.f, 0.f};
#pragma unroll
    for (int r = 0; r < 4; ++r) { mrun[mf][r] = -1e30f; lrun[mf][r] = 0.f; }
  }

  for (int t = 0; t < 32; ++t) {
    int kv0 = t * 64;

    // ---- QK^T: K fragments straight from L2 ----
    f32x4 sa[2][4];
#pragma unroll
    for (int mf = 0; mf < 2; ++mf)
#pragma unroll
      for (int nf = 0; nf < 4; ++nf) sa[mf][nf] = f32x4{0.f, 0.f, 0.f, 0.f};
#pragma unroll
    for (int kf = 0; kf < 4; ++kf) {
      s16x8 kb[4];
#pragma unroll
      for (int nf = 0; nf < 4; ++nf)
        kb[nf] = *(const s16x8*)(Kb + (size_t)(kv0 + nf * 16 + l15) * 6144 + kf * 32 + l4 * 8);
      __builtin_amdgcn_s_setprio(1);
#pragma unroll
      for (int mf = 0; mf < 2; ++mf)
#pragma unroll
        for (int nf = 0; nf < 4; ++nf)
          sa[mf][nf] = __builtin_amdgcn_mfma_f32_16x16x32_bf16(qf[mf][kf], kb[nf], sa[mf][nf], 0, 0, 0);
      __builtin_amdgcn_s_setprio(0);
    }

    // ---- online softmax (wave-parallel, 16-lane groups) ----
    float fs[2][4];
#pragma unroll
    for (int mf = 0; mf < 2; ++mf) {
      float rmax[4], rsum[4];
#pragma unroll
      for (int r = 0; r < 4; ++r)
        rmax[r] = fmaxf(fmaxf(sa[mf][0][r], sa[mf][1][r]), fmaxf(sa[mf][2][r], sa[mf][3][r]));
#pragma unroll
      for (int d = 1; d < 16; d <<= 1)
#pragma unroll
        for (int r = 0; r < 4; ++r) rmax[r] = fmaxf(rmax[r], __shfl_xor(rmax[r], d, 64));
      u16 pw[4][4];
#pragma unroll
      for (int r = 0; r < 4; ++r) {
        float mnew = fmaxf(mrun[mf][r], rmax[r]);
        fs[mf][r] = exp2f((mrun[mf][r] - mnew) * ksc);
        mrun[mf][r] = mnew;
        rsum[r] = 0.f;
#pragma unroll
        for (int nf = 0; nf < 4; ++nf) {
          float p = exp2f((sa[mf][nf][r] - mnew) * ksc);
          rsum[r] += p;
          pw[nf][r] = f2bf(p);
        }
      }
#pragma unroll
      for (int d = 1; d < 16; d <<= 1)
#pragma unroll
        for (int r = 0; r < 4; ++r) rsum[r] += __shfl_xor(rsum[r], d, 64);
#pragma unroll
      for (int r = 0; r < 4; ++r) lrun[mf][r] = lrun[mf][r] * fs[mf][r] + rsum[r];
#pragma unroll
      for (int nf = 0; nf < 4; ++nf)
#pragma unroll
        for (int r = 0; r < 4; ++r)
          Ps[wave][mf * 16 + l4 * 4 + r][nf * 16 + l15] = pw[nf][r];
    }
    // Ps is per-wave; same-wave LDS ops are in-order -> no barrier.

    // rescale O
#pragma unroll
    for (int mf = 0; mf < 2; ++mf)
#pragma unroll
      for (int n2 = 0; n2 < 8; ++n2)
#pragma unroll
        for (int r = 0; r < 4; ++r) po[mf][n2][r] *= fs[mf][r];

    // ---- P fragments ----
    s16x8 pa[2][2];
#pragma unroll
    for (int mf = 0; mf < 2; ++mf)
#pragma unroll
      for (int k2 = 0; k2 < 2; ++k2)
        pa[mf][k2] = *(const s16x8*)&Ps[wave][mf * 16 + l15][k2 * 32 + l4 * 8];

    // ---- PV: V fragments straight from L2 ----
#pragma unroll
    for (int n2 = 0; n2 < 8; ++n2) {
      s16x8 vb[2];
#pragma unroll
      for (int k2 = 0; k2 < 2; ++k2)
        vb[k2] = *(const s16x8*)(Vb + (size_t)(n2 * 16 + l15) * 2048 + kv0 + (k2 * 4 + l4) * 8);
      __builtin_amdgcn_s_setprio(1);
#pragma unroll
      for (int k2 = 0; k2 < 2; ++k2)
#pragma unroll
        for (int mf = 0; mf < 2; ++mf)
          po[mf][n2] = __builtin_amdgcn_mfma_f32_16x16x32_bf16(pa[mf][k2], vb[k2], po[mf][n2], 0, 0, 0);
      __builtin_amdgcn_s_setprio(0);
    }
  }

  // epilogue: normalize + store token-major
#pragma unroll
  for (int mf = 0; mf < 2; ++mf) {
    float inv[4];
#pragma unroll
    for (int r = 0; r < 4; ++r) inv[r] = 1.0f / lrun[mf][r];
#pragma unroll
    for (int n2 = 0; n2 < 8; ++n2)
#pragma unroll
      for (int r = 0; r < 4; ++r)
        outl[(size_t)(b * 2048 + q0 + mf * 16 + l4 * 4 + r) * 2048 + h * 128 + n2 * 16 + l15] =
            f2bf(po[mf][n2][r] * inv[r]);
  }
}

extern "C" void kernel_launch(void* const* d_in, const int* in_sizes, int n_in,
                              void* d_out, int out_size, void* d_ws, size_t ws_size,
                              hipStream_t stream) {
  (void)in_sizes; (void)n_in;
  const float* hs  = (const float*)d_in[0];
  const float* Wq  = (const float*)d_in[1];
  const float* Wkd = (const float*)d_in[2];
  const float* Wvd = (const float*)d_in[3];
  const float* Wku = (const float*)d_in[4];
  const float* Wo  = (const float*)d_in[5];
  float* out = (float*)d_out;
  char* ws = (char*)d_ws;

  // ws sentinel: need 192 MiB
  if (ws_size < 201326592ull) {
    fill_k<<<4096, 256, 0, stream>>>(out, out_size, 1e9f);
    return;
  }

  // workspace layout (bytes), total 192 MiB, time-multiplexed:
  //  [0,   25.17M) W3 (live -> qkv GEMM); then WcL at [0, 8.39M)
  //  [25.17M, 33.55M) WcH
  //  [33.55M, 50.33M) hsB (live -> qkv GEMM)
  //  [41.94M, 67.11M) WkuT|WoH|WoL (live after qkv GEMM -> Wc GEMM)
  //  [33.55M, 67.11M) outl (after Wc GEMM)
  //  [67.11M, 167.77M) qkv
  //  [167.77M, 201.33M) Vt
  u16* W3   = (u16*)(ws);
  u16* WcL  = (u16*)(ws);
  u16* WcH  = (u16*)(ws + 25165824);
  u16* hsB  = (u16*)(ws + 33554432);
  u16* WkuT = (u16*)(ws + 41943040);
  u16* WoH  = (u16*)(ws + 50331648);
  u16* WoL  = (u16*)(ws + 58720256);
  u16* outl = (u16*)(ws + 33554432);
  u16* qkv  = (u16*)(ws + 67108864);
  u16* Vt   = (u16*)(ws + 167772160);

  cvt_k<<<16384, 256, 0, stream>>>(hs, hsB, 4194304);
  cvt_k<<<4096, 256, 0, stream>>>(Wq, W3, 1048576);
  cvt_k<<<4096, 256, 0, stream>>>(Wkd, W3 + 4194304, 1048576);
  cvt_k<<<4096, 256, 0, stream>>>(Wvd, W3 + 8388608, 1048576);

  // qkv = hsB @ [Wq|Wk_down|Wv_down]^T
  btgemm_k<u16, 1, 1><<<3072, 256, 0, stream>>>(hsB, W3, nullptr, nullptr,
                                                qkv, nullptr, 8192, 6144, 2048);

  // Wku/Wo (regions freed by qkv GEMM completion; stream-ordered)
  cvtT_k<<<dim3(64, 64), dim3(32, 8), 0, stream>>>(Wku, WkuT);
  cvt2_k<<<4096, 256, 0, stream>>>(Wo, WoH, WoL, 1048576);

  // Wc = (WoH + WoL) @ WkuT^T   (2 passes), output hi+lo pair
  btgemm_k<u16, 2, 2><<<256, 256, 0, stream>>>(WoH, WkuT, WoL, WkuT,
                                               WcH, WcL, 2048, 2048, 2048);

  vtrans_k<<<dim3(4, 64, 64), dim3(32, 8), 0, stream>>>(qkv, Vt);
  attn4_k<<<1024, 256, 0, stream>>>(qkv, Vt, outl);

  // out = out_lat @ (WcH + WcL)^T   (split-B, 2 passes, fp32 out)
  btgemm_k<float, 0, 2><<<1024, 256, 0, stream>>>(outl, WcH, outl, WcL,
                                                  out, nullptr, 8192, 2048, 2048);
}

// Round 7
// 935.379 us; speedup vs baseline: 1.2223x; 1.2223x over previous
//
#include <hip/hip_runtime.h>
#include <stdint.h>

typedef unsigned short u16;
typedef __attribute__((ext_vector_type(4))) float f32x4;
typedef __attribute__((ext_vector_type(8))) short s16x8;
typedef __attribute__((ext_vector_type(4))) u16 u16x4;

__device__ __forceinline__ u16 f2bf(float x) {
  union { float f; uint32_t u; } v; v.f = x;
  uint32_t r = v.u + 0x7FFFu + ((v.u >> 16) & 1u);
  return (u16)(r >> 16);
}
__device__ __forceinline__ float bf2f(u16 b) {
  union { uint32_t u; float f; } v; v.u = ((uint32_t)b) << 16;
  return v.f;
}

__device__ __forceinline__ void gload16(const void* g, const void* l) {
  __builtin_amdgcn_global_load_lds((const __attribute__((address_space(1))) void*)g,
                                   (__attribute__((address_space(3))) void*)l,
                                   16, 0, 0);
}

__global__ void fill_k(float* out, int n, float v) {
  for (int i = blockIdx.x * blockDim.x + threadIdx.x; i < n; i += gridDim.x * blockDim.x)
    out[i] = v;
}

// ---------------- fp32 -> bf16 convert (vectorized) ----------------
__global__ void cvt_k(const float* __restrict__ in, u16* __restrict__ out, int n4) {
  int i = blockIdx.x * blockDim.x + threadIdx.x;
  if (i >= n4) return;
  f32x4 v = ((const f32x4*)in)[i];
  u16x4 o;
  o.x = f2bf(v.x); o.y = f2bf(v.y); o.z = f2bf(v.z); o.w = f2bf(v.w);
  ((u16x4*)out)[i] = o;
}

// ---------------- fp32 -> bf16 hi+lo split ----------------
__global__ void cvt2_k(const float* __restrict__ in, u16* __restrict__ hi,
                       u16* __restrict__ lo, int n4) {
  int i = blockIdx.x * blockDim.x + threadIdx.x;
  if (i >= n4) return;
  f32x4 v = ((const f32x4*)in)[i];
  u16x4 h, l;
#pragma unroll
  for (int j = 0; j < 4; ++j) {
    u16 hb = f2bf(v[j]);
    h[j] = hb;
    l[j] = f2bf(v[j] - bf2f(hb));
  }
  ((u16x4*)hi)[i] = h;
  ((u16x4*)lo)[i] = l;
}

// ------------- fp32 [2048][2048] -> bf16 transposed -------------
__global__ void cvtT_k(const float* __restrict__ in, u16* __restrict__ out) {
  __shared__ float t[32][33];
  int tx = threadIdx.x, ty = threadIdx.y;
  int c = blockIdx.x * 32 + tx;
#pragma unroll
  for (int j = 0; j < 4; ++j) {
    int r = blockIdx.y * 32 + ty + j * 8;
    t[ty + j * 8][tx] = in[(size_t)r * 2048 + c];
  }
  __syncthreads();
  int c2 = blockIdx.y * 32 + tx;
#pragma unroll
  for (int j = 0; j < 4; ++j) {
    int r2 = blockIdx.x * 32 + ty + j * 8;
    out[(size_t)r2 * 2048 + c2] = f2bf(t[tx][ty + j * 8]);
  }
}

// ------------- per-head V transpose: qkv[:,4096+h*128+dh] -> Vt[bh][dh][s] -------------
__global__ void vtrans_k(const u16* __restrict__ qkv, u16* __restrict__ Vt) {
  __shared__ u16 t[32][34];
  int bh = blockIdx.z; int b = bh >> 4, h = bh & 15;
  int tx = threadIdx.x, ty = threadIdx.y;
  int dh = blockIdx.x * 32 + tx;
#pragma unroll
  for (int j = 0; j < 4; ++j) {
    int s = blockIdx.y * 32 + ty + j * 8;
    t[ty + j * 8][tx] = qkv[(size_t)(b * 2048 + s) * 6144 + 4096 + h * 128 + dh];
  }
  __syncthreads();
  int s2 = blockIdx.y * 32 + tx;
#pragma unroll
  for (int j = 0; j < 4; ++j) {
    int dh2 = blockIdx.x * 32 + ty + j * 8;
    Vt[(size_t)(bh * 128 + dh2) * 2048 + s2] = t[tx][ty + j * 8];
  }
}

// ------------- bf16 GEMM: C = sum_p A_p[M][K] * B_p[N][K]^T  (split-precision passes) ----
// OUTMODE: 0 = fp32, 1 = bf16, 2 = bf16 hi+lo pair (C, C2)
template <typename CT, int OUTMODE, int NP>
__global__ __launch_bounds__(256) void btgemm_k(const u16* __restrict__ A0,
                                                const u16* __restrict__ B0,
                                                const u16* __restrict__ A1,
                                                const u16* __restrict__ B1,
                                                CT* __restrict__ C,
                                                u16* __restrict__ C2,
                                                int M, int N, int K) {
  __shared__ u16 As[128 * 64];
  __shared__ u16 Bs[128 * 64];
  int nnt = N >> 7;
  int bid = blockIdx.x;
  int nwg = gridDim.x;
  if ((nwg & 7) == 0) { int q = nwg >> 3; bid = (bid & 7) * q + (bid >> 3); }  // XCD swizzle
  int mt = bid / nnt, nt = bid - mt * nnt;
  int tid = threadIdx.x, wave = tid >> 6, lane = tid & 63;
  int l15 = lane & 15, l4 = lane >> 4;
  int wr = wave >> 1, wc = wave & 1;
  int sr = lane >> 3, sc = lane & 7;
  int gsl = (sc ^ sr) * 8;  // pre-swizzled source slot (elements)

  const u16* Alist[2] = {A0, A1};
  const u16* Blist[2] = {B0, B1};
  size_t aoff = (size_t)(mt * 128 + wave * 32 + sr) * K + gsl;
  size_t boff = (size_t)(nt * 128 + wave * 32 + sr) * K + gsl;
  u16* Asw = As + wave * 32 * 64;
  u16* Bsw = Bs + wave * 32 * 64;

  f32x4 acc[4][4];
#pragma unroll
  for (int i = 0; i < 4; ++i)
#pragma unroll
    for (int j = 0; j < 4; ++j) acc[i][j] = f32x4{0.f, 0.f, 0.f, 0.f};

#pragma unroll
  for (int p = 0; p < NP; ++p) {
    const u16* Ag = Alist[p] + aoff;
    const u16* Bg = Blist[p] + boff;
    for (int kt = 0; kt < K; kt += 64) {
#pragma unroll
      for (int i = 0; i < 4; ++i) {
        gload16(Ag + kt + i * 8 * K, Asw + i * 512);
        gload16(Bg + kt + i * 8 * K, Bsw + i * 512);
      }
      __syncthreads();
#pragma unroll
      for (int kk = 0; kk < 2; ++kk) {
        s16x8 af[4], bfr[4];
#pragma unroll
        for (int mf = 0; mf < 4; ++mf) {
          int row = wr * 64 + mf * 16 + l15;
          int sl = ((kk * 4 + l4) ^ (row & 7)) * 8;
          af[mf] = *(const s16x8*)(As + row * 64 + sl);
        }
#pragma unroll
        for (int nf = 0; nf < 4; ++nf) {
          int row = wc * 64 + nf * 16 + l15;
          int sl = ((kk * 4 + l4) ^ (row & 7)) * 8;
          bfr[nf] = *(const s16x8*)(Bs + row * 64 + sl);
        }
#pragma unroll
        for (int mf = 0; mf < 4; ++mf)
#pragma unroll
          for (int nf = 0; nf < 4; ++nf)
            acc[mf][nf] = __builtin_amdgcn_mfma_f32_16x16x32_bf16(af[mf], bfr[nf], acc[mf][nf], 0, 0, 0);
      }
      __syncthreads();
    }
  }

  int crow = mt * 128 + wr * 64 + l4 * 4;
  int ccol = nt * 128 + wc * 64 + l15;
#pragma unroll
  for (int mf = 0; mf < 4; ++mf)
#pragma unroll
    for (int nf = 0; nf < 4; ++nf)
#pragma unroll
      for (int r = 0; r < 4; ++r) {
        size_t idx = (size_t)(crow + mf * 16 + r) * N + (ccol + nf * 16);
        float v = acc[mf][nf][r];
        if constexpr (OUTMODE == 0) {
          C[idx] = v;
        } else if constexpr (OUTMODE == 1) {
          C[idx] = f2bf(v);
        } else {
          u16 hb = f2bf(v);
          C[idx] = hb;
          C2[idx] = f2bf(v - bf2f(hb));
        }
      }
}

// ------------- MFMA flash attention v5 = v3 + bh->XCD locality swizzle -------------
// qkv: [8192][6144] bf16 token-major. Vt: [64][128][2048] bf16. outl: [8192][2048] bf16.
// Grid 1024 1-D. xcd = bid&7 owns bh in [8*xcd, 8*xcd+8); qb sequential within bh, so
// each XCD's L2 holds the 1MB K/V of the ~2-3 bh active on it (was: scattered, 2.8x refetch).
__global__ __launch_bounds__(256) void attn5_k(const u16* __restrict__ qkv,
                                               const u16* __restrict__ Vt,
                                               u16* __restrict__ outl) {
  __shared__ u16 Ks[64 * 128];   // [kv][d], 256B rows, XOR-swizzled 16B slots
  __shared__ u16 Vs[128 * 64];   // [dh][kv], 128B rows, XOR-swizzled
  __shared__ u16 Ps[4][32][72];  // per-wave P tile

  int bid = blockIdx.x;
  int xcd = bid & 7, slot = bid >> 3;          // dispatch round-robins XCDs on bid&7
  int bh = xcd * 8 + (slot >> 4), qb = slot & 15;
  int b = bh >> 4, h = bh & 15;
  int tid = threadIdx.x, wave = tid >> 6, lane = tid & 63;
  int l15 = lane & 15, l4 = lane >> 4;
  int q0 = qb * 128 + wave * 32;
  const float ksc = 0.12751743f;  // log2(e)/sqrt(128)

  s16x8 qf[2][4];
#pragma unroll
  for (int mf = 0; mf < 2; ++mf)
#pragma unroll
    for (int kf = 0; kf < 4; ++kf)
      qf[mf][kf] = *(const s16x8*)(qkv + (size_t)(b * 2048 + q0 + mf * 16 + l15) * 6144 +
                                   h * 128 + kf * 32 + l4 * 8);

  f32x4 po[2][8];
  float mrun[2][4], lrun[2][4];
#pragma unroll
  for (int mf = 0; mf < 2; ++mf) {
#pragma unroll
    for (int n2 = 0; n2 < 8; ++n2) po[mf][n2] = f32x4{0.f, 0.f, 0.f, 0.f};
#pragma unroll
    for (int r = 0; r < 4; ++r) { mrun[mf][r] = -1e30f; lrun[mf][r] = 0.f; }
  }

  int krow_b = wave * 16;   // wave's K rows: +i*4 + (lane>>4)
  int vrow_b = wave * 32;   // wave's V rows: +i*8 + (lane>>3)
  int kj = lane & 15;       // K 16B slot within row (of 16)
  int vj = lane & 7;        // V 16B slot within row (of 8)

  s16x8 kr[4], vr[4];       // T14: in-flight next tile
#define GLOAD_TILE(kv0)                                                                  \
  _Pragma("unroll") for (int i = 0; i < 4; ++i) {                                        \
    int row = krow_b + i * 4 + (lane >> 4);                                              \
    kr[i] = *(const s16x8*)(qkv + (size_t)(b * 2048 + (kv0) + row) * 6144 + 2048 +       \
                            h * 128 + kj * 8);                                           \
    int row2 = vrow_b + i * 8 + (lane >> 3);                                             \
    vr[i] = *(const s16x8*)(Vt + (size_t)(bh * 128 + row2) * 2048 + (kv0) + vj * 8);     \
  }

  GLOAD_TILE(0)

  for (int t = 0; t < 32; ++t) {
    __syncthreads();  // previous tile's Ks/Vs reads done
    // ---- write staged regs to LDS (swizzled) ----
#pragma unroll
    for (int i = 0; i < 4; ++i) {
      int row = krow_b + i * 4 + (lane >> 4);
      *(s16x8*)(Ks + row * 128 + ((kj ^ (row & 7)) * 8)) = kr[i];
      int row2 = vrow_b + i * 8 + (lane >> 3);
      *(s16x8*)(Vs + row2 * 64 + ((vj ^ (row2 & 7)) * 8)) = vr[i];
    }
    __syncthreads();  // staging visible
    // ---- issue next tile's global loads; land during compute ----
    if (t < 31) GLOAD_TILE((t + 1) * 64)

    // ---- QK^T ----
    f32x4 sa[2][4];
#pragma unroll
    for (int mf = 0; mf < 2; ++mf)
#pragma unroll
      for (int nf = 0; nf < 4; ++nf) sa[mf][nf] = f32x4{0.f, 0.f, 0.f, 0.f};
    __builtin_amdgcn_s_setprio(1);
#pragma unroll
    for (int kf = 0; kf < 4; ++kf) {
      s16x8 kb[4];
#pragma unroll
      for (int nf = 0; nf < 4; ++nf) {
        int row = nf * 16 + l15;
        int sl = ((kf * 4 + l4) ^ (row & 7)) * 8;
        kb[nf] = *(const s16x8*)(Ks + row * 128 + sl);
      }
#pragma unroll
      for (int mf = 0; mf < 2; ++mf)
#pragma unroll
        for (int nf = 0; nf < 4; ++nf)
          sa[mf][nf] = __builtin_amdgcn_mfma_f32_16x16x32_bf16(qf[mf][kf], kb[nf], sa[mf][nf], 0, 0, 0);
    }
    __builtin_amdgcn_s_setprio(0);

    // ---- online softmax (wave-parallel, 16-lane groups) ----
    float fs[2][4];
#pragma unroll
    for (int mf = 0; mf < 2; ++mf) {
      float rmax[4], rsum[4];
#pragma unroll
      for (int r = 0; r < 4; ++r)
        rmax[r] = fmaxf(fmaxf(sa[mf][0][r], sa[mf][1][r]), fmaxf(sa[mf][2][r], sa[mf][3][r]));
#pragma unroll
      for (int d = 1; d < 16; d <<= 1)
#pragma unroll
        for (int r = 0; r < 4; ++r) rmax[r] = fmaxf(rmax[r], __shfl_xor(rmax[r], d, 64));
      u16 pw[4][4];
#pragma unroll
      for (int r = 0; r < 4; ++r) {
        float mnew = fmaxf(mrun[mf][r], rmax[r]);
        fs[mf][r] = exp2f((mrun[mf][r] - mnew) * ksc);
        mrun[mf][r] = mnew;
        rsum[r] = 0.f;
#pragma unroll
        for (int nf = 0; nf < 4; ++nf) {
          float p = exp2f((sa[mf][nf][r] - mnew) * ksc);
          rsum[r] += p;
          pw[nf][r] = f2bf(p);
        }
      }
#pragma unroll
      for (int d = 1; d < 16; d <<= 1)
#pragma unroll
        for (int r = 0; r < 4; ++r) rsum[r] += __shfl_xor(rsum[r], d, 64);
#pragma unroll
      for (int r = 0; r < 4; ++r) lrun[mf][r] = lrun[mf][r] * fs[mf][r] + rsum[r];
#pragma unroll
      for (int nf = 0; nf < 4; ++nf)
#pragma unroll
        for (int r = 0; r < 4; ++r)
          Ps[wave][mf * 16 + l4 * 4 + r][nf * 16 + l15] = pw[nf][r];
    }
    // Ps is per-wave; same-wave LDS ops are in-order -> no barrier.

    // rescale O
#pragma unroll
    for (int mf = 0; mf < 2; ++mf)
#pragma unroll
      for (int n2 = 0; n2 < 8; ++n2)
#pragma unroll
        for (int r = 0; r < 4; ++r) po[mf][n2][r] *= fs[mf][r];

    // ---- P fragments ----
    s16x8 pa[2][2];
#pragma unroll
    for (int mf = 0; mf < 2; ++mf)
#pragma unroll
      for (int k2 = 0; k2 < 2; ++k2)
        pa[mf][k2] = *(const s16x8*)&Ps[wave][mf * 16 + l15][k2 * 32 + l4 * 8];

    // ---- PV ----
    __builtin_amdgcn_s_setprio(1);
#pragma unroll
    for (int n2 = 0; n2 < 8; ++n2) {
#pragma unroll
      for (int k2 = 0; k2 < 2; ++k2) {
        int row = n2 * 16 + l15;
        int sl = ((k2 * 4 + l4) ^ (row & 7)) * 8;
        s16x8 vb = *(const s16x8*)(Vs + row * 64 + sl);
#pragma unroll
        for (int mf = 0; mf < 2; ++mf)
          po[mf][n2] = __builtin_amdgcn_mfma_f32_16x16x32_bf16(pa[mf][k2], vb, po[mf][n2], 0, 0, 0);
      }
    }
    __builtin_amdgcn_s_setprio(0);
  }
#undef GLOAD_TILE

  // epilogue: normalize + store token-major
#pragma unroll
  for (int mf = 0; mf < 2; ++mf) {
    float inv[4];
#pragma unroll
    for (int r = 0; r < 4; ++r) inv[r] = 1.0f / lrun[mf][r];
#pragma unroll
    for (int n2 = 0; n2 < 8; ++n2)
#pragma unroll
      for (int r = 0; r < 4; ++r)
        outl[(size_t)(b * 2048 + q0 + mf * 16 + l4 * 4 + r) * 2048 + h * 128 + n2 * 16 + l15] =
            f2bf(po[mf][n2][r] * inv[r]);
  }
}

extern "C" void kernel_launch(void* const* d_in, const int* in_sizes, int n_in,
                              void* d_out, int out_size, void* d_ws, size_t ws_size,
                              hipStream_t stream) {
  (void)in_sizes; (void)n_in;
  const float* hs  = (const float*)d_in[0];
  const float* Wq  = (const float*)d_in[1];
  const float* Wkd = (const float*)d_in[2];
  const float* Wvd = (const float*)d_in[3];
  const float* Wku = (const float*)d_in[4];
  const float* Wo  = (const float*)d_in[5];
  float* out = (float*)d_out;
  char* ws = (char*)d_ws;

  // ws sentinel: need 192 MiB
  if (ws_size < 201326592ull) {
    fill_k<<<4096, 256, 0, stream>>>(out, out_size, 1e9f);
    return;
  }

  u16* W3   = (u16*)(ws);
  u16* WcL  = (u16*)(ws);
  u16* WcH  = (u16*)(ws + 25165824);
  u16* hsB  = (u16*)(ws + 33554432);
  u16* WkuT = (u16*)(ws + 41943040);
  u16* WoH  = (u16*)(ws + 50331648);
  u16* WoL  = (u16*)(ws + 58720256);
  u16* outl = (u16*)(ws + 33554432);
  u16* qkv  = (u16*)(ws + 67108864);
  u16* Vt   = (u16*)(ws + 167772160);

  cvt_k<<<16384, 256, 0, stream>>>(hs, hsB, 4194304);
  cvt_k<<<4096, 256, 0, stream>>>(Wq, W3, 1048576);
  cvt_k<<<4096, 256, 0, stream>>>(Wkd, W3 + 4194304, 1048576);
  cvt_k<<<4096, 256, 0, stream>>>(Wvd, W3 + 8388608, 1048576);

  // qkv = hsB @ [Wq|Wk_down|Wv_down]^T
  btgemm_k<u16, 1, 1><<<3072, 256, 0, stream>>>(hsB, W3, nullptr, nullptr,
                                                qkv, nullptr, 8192, 6144, 2048);

  // Wku/Wo (regions freed by qkv GEMM completion; stream-ordered)
  cvtT_k<<<dim3(64, 64), dim3(32, 8), 0, stream>>>(Wku, WkuT);
  cvt2_k<<<4096, 256, 0, stream>>>(Wo, WoH, WoL, 1048576);

  // Wc = (WoH + WoL) @ WkuT^T   (2 passes), output hi+lo pair
  btgemm_k<u16, 2, 2><<<256, 256, 0, stream>>>(WoH, WkuT, WoL, WkuT,
                                               WcH, WcL, 2048, 2048, 2048);

  vtrans_k<<<dim3(4, 64, 64), dim3(32, 8), 0, stream>>>(qkv, Vt);
  attn5_k<<<1024, 256, 0, stream>>>(qkv, Vt, outl);

  // out = out_lat @ (WcH + WcL)^T   (split-B, 2 passes, fp32 out)
  btgemm_k<float, 0, 2><<<1024, 256, 0, stream>>>(outl, WcH, outl, WcL,
                                                  out, nullptr, 8192, 2048, 2048);
}

// Round 8
// 816.558 us; speedup vs baseline: 1.4002x; 1.1455x over previous
//
#include <hip/hip_runtime.h>
#include <stdint.h>

typedef unsigned short u16;
typedef __attribute__((ext_vector_type(4))) float f32x4;
typedef __attribute__((ext_vector_type(8))) short s16x8;
typedef __attribute__((ext_vector_type(4))) u16 u16x4;

__device__ __forceinline__ u16 f2bf(float x) {
  union { float f; uint32_t u; } v; v.f = x;
  uint32_t r = v.u + 0x7FFFu + ((v.u >> 16) & 1u);
  return (u16)(r >> 16);
}
__device__ __forceinline__ float bf2f(u16 b) {
  union { uint32_t u; float f; } v; v.u = ((uint32_t)b) << 16;
  return v.f;
}

__device__ __forceinline__ void gload16(const void* g, const void* l) {
  __builtin_amdgcn_global_load_lds((const __attribute__((address_space(1))) void*)g,
                                   (__attribute__((address_space(3))) void*)l,
                                   16, 0, 0);
}

__global__ void fill_k(float* out, int n, float v) {
  for (int i = blockIdx.x * blockDim.x + threadIdx.x; i < n; i += gridDim.x * blockDim.x)
    out[i] = v;
}

// ---------------- fp32 -> bf16 convert (vectorized) ----------------
__global__ void cvt_k(const float* __restrict__ in, u16* __restrict__ out, int n4) {
  int i = blockIdx.x * blockDim.x + threadIdx.x;
  if (i >= n4) return;
  f32x4 v = ((const f32x4*)in)[i];
  u16x4 o;
  o.x = f2bf(v.x); o.y = f2bf(v.y); o.z = f2bf(v.z); o.w = f2bf(v.w);
  ((u16x4*)out)[i] = o;
}

// ---------------- fp32 -> bf16 hi+lo split ----------------
__global__ void cvt2_k(const float* __restrict__ in, u16* __restrict__ hi,
                       u16* __restrict__ lo, int n4) {
  int i = blockIdx.x * blockDim.x + threadIdx.x;
  if (i >= n4) return;
  f32x4 v = ((const f32x4*)in)[i];
  u16x4 h, l;
#pragma unroll
  for (int j = 0; j < 4; ++j) {
    u16 hb = f2bf(v[j]);
    h[j] = hb;
    l[j] = f2bf(v[j] - bf2f(hb));
  }
  ((u16x4*)hi)[i] = h;
  ((u16x4*)lo)[i] = l;
}

// ------------- fp32 [2048][2048] -> bf16 transposed -------------
__global__ void cvtT_k(const float* __restrict__ in, u16* __restrict__ out) {
  __shared__ float t[32][33];
  int tx = threadIdx.x, ty = threadIdx.y;
  int c = blockIdx.x * 32 + tx;
#pragma unroll
  for (int j = 0; j < 4; ++j) {
    int r = blockIdx.y * 32 + ty + j * 8;
    t[ty + j * 8][tx] = in[(size_t)r * 2048 + c];
  }
  __syncthreads();
  int c2 = blockIdx.y * 32 + tx;
#pragma unroll
  for (int j = 0; j < 4; ++j) {
    int r2 = blockIdx.x * 32 + ty + j * 8;
    out[(size_t)r2 * 2048 + c2] = f2bf(t[tx][ty + j * 8]);
  }
}

// ------------- per-head V transpose: qkv[:,4096+h*128+dh] -> Vt[bh][dh][s] -------------
__global__ void vtrans_k(const u16* __restrict__ qkv, u16* __restrict__ Vt) {
  __shared__ u16 t[32][34];
  int bh = blockIdx.z; int b = bh >> 4, h = bh & 15;
  int tx = threadIdx.x, ty = threadIdx.y;
  int dh = blockIdx.x * 32 + tx;
#pragma unroll
  for (int j = 0; j < 4; ++j) {
    int s = blockIdx.y * 32 + ty + j * 8;
    t[ty + j * 8][tx] = qkv[(size_t)(b * 2048 + s) * 6144 + 4096 + h * 128 + dh];
  }
  __syncthreads();
  int s2 = blockIdx.y * 32 + tx;
#pragma unroll
  for (int j = 0; j < 4; ++j) {
    int dh2 = blockIdx.x * 32 + ty + j * 8;
    Vt[(size_t)(bh * 128 + dh2) * 2048 + s2] = t[tx][ty + j * 8];
  }
}

// ------------- bf16 GEMM: C = sum_p A_p[M][K] * B_p[N][K]^T  (split-precision passes) ----
// OUTMODE: 0 = fp32, 1 = bf16, 2 = bf16 hi+lo pair (C, C2)
template <typename CT, int OUTMODE, int NP>
__global__ __launch_bounds__(256) void btgemm_k(const u16* __restrict__ A0,
                                                const u16* __restrict__ B0,
                                                const u16* __restrict__ A1,
                                                const u16* __restrict__ B1,
                                                CT* __restrict__ C,
                                                u16* __restrict__ C2,
                                                int M, int N, int K) {
  __shared__ u16 As[128 * 64];
  __shared__ u16 Bs[128 * 64];
  int nnt = N >> 7;
  int bid = blockIdx.x;
  int nwg = gridDim.x;
  if ((nwg & 7) == 0) { int q = nwg >> 3; bid = (bid & 7) * q + (bid >> 3); }  // XCD swizzle
  int mt = bid / nnt, nt = bid - mt * nnt;
  int tid = threadIdx.x, wave = tid >> 6, lane = tid & 63;
  int l15 = lane & 15, l4 = lane >> 4;
  int wr = wave >> 1, wc = wave & 1;
  int sr = lane >> 3, sc = lane & 7;
  int gsl = (sc ^ sr) * 8;  // pre-swizzled source slot (elements)

  const u16* Alist[2] = {A0, A1};
  const u16* Blist[2] = {B0, B1};
  size_t aoff = (size_t)(mt * 128 + wave * 32 + sr) * K + gsl;
  size_t boff = (size_t)(nt * 128 + wave * 32 + sr) * K + gsl;
  u16* Asw = As + wave * 32 * 64;
  u16* Bsw = Bs + wave * 32 * 64;

  f32x4 acc[4][4];
#pragma unroll
  for (int i = 0; i < 4; ++i)
#pragma unroll
    for (int j = 0; j < 4; ++j) acc[i][j] = f32x4{0.f, 0.f, 0.f, 0.f};

#pragma unroll
  for (int p = 0; p < NP; ++p) {
    const u16* Ag = Alist[p] + aoff;
    const u16* Bg = Blist[p] + boff;
    for (int kt = 0; kt < K; kt += 64) {
#pragma unroll
      for (int i = 0; i < 4; ++i) {
        gload16(Ag + kt + i * 8 * K, Asw + i * 512);
        gload16(Bg + kt + i * 8 * K, Bsw + i * 512);
      }
      __syncthreads();
#pragma unroll
      for (int kk = 0; kk < 2; ++kk) {
        s16x8 af[4], bfr[4];
#pragma unroll
        for (int mf = 0; mf < 4; ++mf) {
          int row = wr * 64 + mf * 16 + l15;
          int sl = ((kk * 4 + l4) ^ (row & 7)) * 8;
          af[mf] = *(const s16x8*)(As + row * 64 + sl);
        }
#pragma unroll
        for (int nf = 0; nf < 4; ++nf) {
          int row = wc * 64 + nf * 16 + l15;
          int sl = ((kk * 4 + l4) ^ (row & 7)) * 8;
          bfr[nf] = *(const s16x8*)(Bs + row * 64 + sl);
        }
#pragma unroll
        for (int mf = 0; mf < 4; ++mf)
#pragma unroll
          for (int nf = 0; nf < 4; ++nf)
            acc[mf][nf] = __builtin_amdgcn_mfma_f32_16x16x32_bf16(af[mf], bfr[nf], acc[mf][nf], 0, 0, 0);
      }
      __syncthreads();
    }
  }

  int crow = mt * 128 + wr * 64 + l4 * 4;
  int ccol = nt * 128 + wc * 64 + l15;
#pragma unroll
  for (int mf = 0; mf < 4; ++mf)
#pragma unroll
    for (int nf = 0; nf < 4; ++nf)
#pragma unroll
      for (int r = 0; r < 4; ++r) {
        size_t idx = (size_t)(crow + mf * 16 + r) * N + (ccol + nf * 16);
        float v = acc[mf][nf][r];
        if constexpr (OUTMODE == 0) {
          C[idx] = v;
        } else if constexpr (OUTMODE == 1) {
          C[idx] = f2bf(v);
        } else {
          u16 hb = f2bf(v);
          C[idx] = hb;
          C2[idx] = f2bf(v - bf2f(hb));
        }
      }
}

// ------------- MFMA flash attention v6: swapped QK^T, in-register softmax -------------
// P = mfma(K, Q) so each lane owns one q-row slice: row reductions = in-lane tree + 2 shfl.
// Defer-max (T13) skips rescale unless max grows. P->PV via small swizzled LDS roundtrip
// (8x8B writes + 4xb128 reads, per-wave, no barrier). Staging identical to attn5 (green).
__global__ __launch_bounds__(256) void attn6_k(const u16* __restrict__ qkv,
                                               const u16* __restrict__ Vt,
                                               u16* __restrict__ outl) {
  __shared__ u16 Ks[64 * 128];    // [kv][d], XOR-swizzled 16B slots
  __shared__ u16 Vs[128 * 64];    // [dh][kv], XOR-swizzled
  __shared__ u16 Ps2[4 * 32 * 64];// per-wave P[q][kv], XOR-swizzled 16B granules

  int bid = blockIdx.x;
  int xcd = bid & 7, slot = bid >> 3;  // bh->XCD locality (attn5, keeps FETCH low)
  int bh = xcd * 8 + (slot >> 4), qb = slot & 15;
  int b = bh >> 4, h = bh & 15;
  int tid = threadIdx.x, wave = tid >> 6, lane = tid & 63;
  int l15 = lane & 15, l4 = lane >> 4;
  int q0 = qb * 128 + wave * 32;
  const float ksc = 0.12751743f;  // log2(e)/sqrt(128)

  s16x8 qf[2][4];
#pragma unroll
  for (int mf = 0; mf < 2; ++mf)
#pragma unroll
    for (int kf = 0; kf < 4; ++kf)
      qf[mf][kf] = *(const s16x8*)(qkv + (size_t)(b * 2048 + q0 + mf * 16 + l15) * 6144 +
                                   h * 128 + kf * 32 + l4 * 8);

  f32x4 po[2][8];
  float mrun[2], lrun[2];
#pragma unroll
  for (int mf = 0; mf < 2; ++mf) {
#pragma unroll
    for (int n2 = 0; n2 < 8; ++n2) po[mf][n2] = f32x4{0.f, 0.f, 0.f, 0.f};
    mrun[mf] = -1e30f; lrun[mf] = 0.f;
  }

  char* PsW = (char*)(Ps2 + wave * 2048);  // this wave's 4KB P region

  int krow_b = wave * 16;
  int vrow_b = wave * 32;
  int kj = lane & 15;
  int vj = lane & 7;

  s16x8 kr[4], vr[4];  // T14: in-flight next tile
#define GLOAD_TILE(kv0)                                                                  \
  _Pragma("unroll") for (int i = 0; i < 4; ++i) {                                        \
    int row = krow_b + i * 4 + (lane >> 4);                                              \
    kr[i] = *(const s16x8*)(qkv + (size_t)(b * 2048 + (kv0) + row) * 6144 + 2048 +       \
                            h * 128 + kj * 8);                                           \
    int row2 = vrow_b + i * 8 + (lane >> 3);                                             \
    vr[i] = *(const s16x8*)(Vt + (size_t)(bh * 128 + row2) * 2048 + (kv0) + vj * 8);     \
  }

  GLOAD_TILE(0)

  for (int t = 0; t < 32; ++t) {
    __syncthreads();
#pragma unroll
    for (int i = 0; i < 4; ++i) {
      int row = krow_b + i * 4 + (lane >> 4);
      *(s16x8*)(Ks + row * 128 + ((kj ^ (row & 7)) * 8)) = kr[i];
      int row2 = vrow_b + i * 8 + (lane >> 3);
      *(s16x8*)(Vs + row2 * 64 + ((vj ^ (row2 & 7)) * 8)) = vr[i];
    }
    __syncthreads();
    if (t < 31) GLOAD_TILE((t + 1) * 64)

    // ---- QK^T (swapped: A=K, B=Q) -> sa[mf][nf]: kv=nf*16+l4*4+r, q=mf*16+l15 ----
    f32x4 sa[2][4];
#pragma unroll
    for (int mf = 0; mf < 2; ++mf)
#pragma unroll
      for (int nf = 0; nf < 4; ++nf) sa[mf][nf] = f32x4{0.f, 0.f, 0.f, 0.f};
    __builtin_amdgcn_s_setprio(1);
#pragma unroll
    for (int kf = 0; kf < 4; ++kf) {
      s16x8 kb[4];
#pragma unroll
      for (int nf = 0; nf < 4; ++nf) {
        int row = nf * 16 + l15;
        int sl = ((kf * 4 + l4) ^ (row & 7)) * 8;
        kb[nf] = *(const s16x8*)(Ks + row * 128 + sl);
      }
#pragma unroll
      for (int mf = 0; mf < 2; ++mf)
#pragma unroll
        for (int nf = 0; nf < 4; ++nf)
          sa[mf][nf] = __builtin_amdgcn_mfma_f32_16x16x32_bf16(kb[nf], qf[mf][kf], sa[mf][nf], 0, 0, 0);
    }
    __builtin_amdgcn_s_setprio(0);

    // ---- in-register online softmax (per mf; lane owns q=mf*16+l15, 16 kv vals) ----
#pragma unroll
    for (int mf = 0; mf < 2; ++mf) {
      float m01 = fmaxf(fmaxf(sa[mf][0][0], sa[mf][0][1]), fmaxf(sa[mf][0][2], sa[mf][0][3]));
      float m23 = fmaxf(fmaxf(sa[mf][1][0], sa[mf][1][1]), fmaxf(sa[mf][1][2], sa[mf][1][3]));
      float m45 = fmaxf(fmaxf(sa[mf][2][0], sa[mf][2][1]), fmaxf(sa[mf][2][2], sa[mf][2][3]));
      float m67 = fmaxf(fmaxf(sa[mf][3][0], sa[mf][3][1]), fmaxf(sa[mf][3][2], sa[mf][3][3]));
      float pmax = fmaxf(fmaxf(m01, m23), fmaxf(m45, m67));
      pmax = fmaxf(pmax, __shfl_xor(pmax, 16, 64));
      pmax = fmaxf(pmax, __shfl_xor(pmax, 32, 64));
      if (!__all((pmax - mrun[mf]) * ksc <= 8.0f)) {  // T13 defer-max
        float mnew = fmaxf(mrun[mf], pmax);
        float fsc = exp2f((mrun[mf] - mnew) * ksc);
        lrun[mf] *= fsc;
#pragma unroll
        for (int n2 = 0; n2 < 8; ++n2)
#pragma unroll
          for (int r = 0; r < 4; ++r) po[mf][n2][r] *= fsc;
        mrun[mf] = mnew;
      }
      int row = mf * 16 + l15;
      int swz = (row & 7) << 4;
      float ssum = 0.f;
#pragma unroll
      for (int nf = 0; nf < 4; ++nf) {
        float p0 = exp2f((sa[mf][nf][0] - mrun[mf]) * ksc);
        float p1 = exp2f((sa[mf][nf][1] - mrun[mf]) * ksc);
        float p2 = exp2f((sa[mf][nf][2] - mrun[mf]) * ksc);
        float p3 = exp2f((sa[mf][nf][3] - mrun[mf]) * ksc);
        ssum += (p0 + p1) + (p2 + p3);
        u16x4 w;
        w.x = f2bf(p0); w.y = f2bf(p1); w.z = f2bf(p2); w.w = f2bf(p3);
        *(u16x4*)(PsW + row * 128 + (((nf * 4 + l4) * 8) ^ swz)) = w;  // kv=nf*16+l4*4..+3
      }
      ssum += __shfl_xor(ssum, 16, 64);
      ssum += __shfl_xor(ssum, 32, 64);
      lrun[mf] += ssum;
    }

    // ---- P fragments (B-operand: q=l15, kv slots k2*32+l4*8..+7) ----
    s16x8 pb[2][2];
#pragma unroll
    for (int mf = 0; mf < 2; ++mf) {
      int row = mf * 16 + l15;
      int swz = (row & 7) << 4;
#pragma unroll
      for (int k2 = 0; k2 < 2; ++k2)
        pb[mf][k2] = *(const s16x8*)(PsW + row * 128 + ((k2 * 64 + l4 * 16) ^ swz));
    }

    // ---- PV (A=V^T, B=P): po[mf][n2]: dh=n2*16+l4*4+r, q=mf*16+l15 ----
    __builtin_amdgcn_s_setprio(1);
#pragma unroll
    for (int n2 = 0; n2 < 8; ++n2) {
#pragma unroll
      for (int k2 = 0; k2 < 2; ++k2) {
        int row = n2 * 16 + l15;
        int sl = ((k2 * 4 + l4) ^ (row & 7)) * 8;
        s16x8 vb = *(const s16x8*)(Vs + row * 64 + sl);
#pragma unroll
        for (int mf = 0; mf < 2; ++mf)
          po[mf][n2] = __builtin_amdgcn_mfma_f32_16x16x32_bf16(vb, pb[mf][k2], po[mf][n2], 0, 0, 0);
      }
    }
    __builtin_amdgcn_s_setprio(0);
  }
#undef GLOAD_TILE

  // epilogue: normalize + vectorized store (token = q0+mf*16+l15, dh = n2*16+l4*4..+3)
#pragma unroll
  for (int mf = 0; mf < 2; ++mf) {
    float inv = 1.0f / lrun[mf];
#pragma unroll
    for (int n2 = 0; n2 < 8; ++n2) {
      u16x4 w;
      w.x = f2bf(po[mf][n2][0] * inv);
      w.y = f2bf(po[mf][n2][1] * inv);
      w.z = f2bf(po[mf][n2][2] * inv);
      w.w = f2bf(po[mf][n2][3] * inv);
      *(u16x4*)(outl + (size_t)(b * 2048 + q0 + mf * 16 + l15) * 2048 + h * 128 +
                n2 * 16 + l4 * 4) = w;
    }
  }
}

extern "C" void kernel_launch(void* const* d_in, const int* in_sizes, int n_in,
                              void* d_out, int out_size, void* d_ws, size_t ws_size,
                              hipStream_t stream) {
  (void)in_sizes; (void)n_in;
  const float* hs  = (const float*)d_in[0];
  const float* Wq  = (const float*)d_in[1];
  const float* Wkd = (const float*)d_in[2];
  const float* Wvd = (const float*)d_in[3];
  const float* Wku = (const float*)d_in[4];
  const float* Wo  = (const float*)d_in[5];
  float* out = (float*)d_out;
  char* ws = (char*)d_ws;

  // ws sentinel: need 192 MiB
  if (ws_size < 201326592ull) {
    fill_k<<<4096, 256, 0, stream>>>(out, out_size, 1e9f);
    return;
  }

  u16* W3   = (u16*)(ws);
  u16* WcL  = (u16*)(ws);
  u16* WcH  = (u16*)(ws + 25165824);
  u16* hsB  = (u16*)(ws + 33554432);
  u16* WkuT = (u16*)(ws + 41943040);
  u16* WoH  = (u16*)(ws + 50331648);
  u16* WoL  = (u16*)(ws + 58720256);
  u16* outl = (u16*)(ws + 33554432);
  u16* qkv  = (u16*)(ws + 67108864);
  u16* Vt   = (u16*)(ws + 167772160);

  cvt_k<<<16384, 256, 0, stream>>>(hs, hsB, 4194304);
  cvt_k<<<4096, 256, 0, stream>>>(Wq, W3, 1048576);
  cvt_k<<<4096, 256, 0, stream>>>(Wkd, W3 + 4194304, 1048576);
  cvt_k<<<4096, 256, 0, stream>>>(Wvd, W3 + 8388608, 1048576);

  // qkv = hsB @ [Wq|Wk_down|Wv_down]^T
  btgemm_k<u16, 1, 1><<<3072, 256, 0, stream>>>(hsB, W3, nullptr, nullptr,
                                                qkv, nullptr, 8192, 6144, 2048);

  // Wku/Wo (regions freed by qkv GEMM completion; stream-ordered)
  cvtT_k<<<dim3(64, 64), dim3(32, 8), 0, stream>>>(Wku, WkuT);
  cvt2_k<<<4096, 256, 0, stream>>>(Wo, WoH, WoL, 1048576);

  // Wc = (WoH + WoL) @ WkuT^T   (2 passes), output hi+lo pair
  btgemm_k<u16, 2, 2><<<256, 256, 0, stream>>>(WoH, WkuT, WoL, WkuT,
                                               WcH, WcL, 2048, 2048, 2048);

  vtrans_k<<<dim3(4, 64, 64), dim3(32, 8), 0, stream>>>(qkv, Vt);
  attn6_k<<<1024, 256, 0, stream>>>(qkv, Vt, outl);

  // out = out_lat @ (WcH + WcL)^T   (split-B, 2 passes, fp32 out)
  btgemm_k<float, 0, 2><<<1024, 256, 0, stream>>>(outl, WcH, outl, WcL,
                                                  out, nullptr, 8192, 2048, 2048);
}

// Round 9
// 711.845 us; speedup vs baseline: 1.6061x; 1.1471x over previous
//
#include <hip/hip_runtime.h>
#include <stdint.h>

typedef unsigned short u16;
typedef __attribute__((ext_vector_type(4))) float f32x4;
typedef __attribute__((ext_vector_type(8))) short s16x8;
typedef __attribute__((ext_vector_type(4))) u16 u16x4;

__device__ __forceinline__ u16 f2bf(float x) {
  union { float f; uint32_t u; } v; v.f = x;
  uint32_t r = v.u + 0x7FFFu + ((v.u >> 16) & 1u);
  return (u16)(r >> 16);
}
__device__ __forceinline__ float bf2f(u16 b) {
  union { uint32_t u; float f; } v; v.u = ((uint32_t)b) << 16;
  return v.f;
}

__device__ __forceinline__ void gload16(const void* g, const void* l) {
  __builtin_amdgcn_global_load_lds((const __attribute__((address_space(1))) void*)g,
                                   (__attribute__((address_space(3))) void*)l,
                                   16, 0, 0);
}

__global__ void fill_k(float* out, int n, float v) {
  for (int i = blockIdx.x * blockDim.x + threadIdx.x; i < n; i += gridDim.x * blockDim.x)
    out[i] = v;
}

// ------------- fused fp32 -> bf16 convert for hs, Wq, Wkd, Wvd, Wo (one launch) -------------
__global__ void cvtall_k(const float* __restrict__ hs, const float* __restrict__ Wq,
                         const float* __restrict__ Wkd, const float* __restrict__ Wvd,
                         const float* __restrict__ Wo,
                         u16* __restrict__ hsB, u16* __restrict__ W3, u16* __restrict__ WoB) {
  int i = blockIdx.x * blockDim.x + threadIdx.x;  // f32x4 units, total 8388608
  const float* src; u16* dst; int off;
  if (i < 4194304)      { src = hs;  dst = hsB;          off = i; }
  else if (i < 5242880) { src = Wq;  dst = W3;           off = i - 4194304; }
  else if (i < 6291456) { src = Wkd; dst = W3 + 4194304; off = i - 5242880; }
  else if (i < 7340032) { src = Wvd; dst = W3 + 8388608; off = i - 6291456; }
  else                  { src = Wo;  dst = WoB;          off = i - 7340032; }
  f32x4 v = ((const f32x4*)src)[off];
  u16x4 o;
  o.x = f2bf(v.x); o.y = f2bf(v.y); o.z = f2bf(v.z); o.w = f2bf(v.w);
  ((u16x4*)dst)[off] = o;
}

// ------------- fp32 [2048][2048] -> bf16 transposed -------------
__global__ void cvtT_k(const float* __restrict__ in, u16* __restrict__ out) {
  __shared__ float t[32][33];
  int tx = threadIdx.x, ty = threadIdx.y;
  int c = blockIdx.x * 32 + tx;
#pragma unroll
  for (int j = 0; j < 4; ++j) {
    int r = blockIdx.y * 32 + ty + j * 8;
    t[ty + j * 8][tx] = in[(size_t)r * 2048 + c];
  }
  __syncthreads();
  int c2 = blockIdx.y * 32 + tx;
#pragma unroll
  for (int j = 0; j < 4; ++j) {
    int r2 = blockIdx.x * 32 + ty + j * 8;
    out[(size_t)r2 * 2048 + c2] = f2bf(t[tx][ty + j * 8]);
  }
}

// ------------- per-head V transpose: qkv[:,4096+h*128+dh] -> Vt[bh][dh][s] -------------
__global__ void vtrans_k(const u16* __restrict__ qkv, u16* __restrict__ Vt) {
  __shared__ u16 t[32][34];
  int bh = blockIdx.z; int b = bh >> 4, h = bh & 15;
  int tx = threadIdx.x, ty = threadIdx.y;
  int dh = blockIdx.x * 32 + tx;
#pragma unroll
  for (int j = 0; j < 4; ++j) {
    int s = blockIdx.y * 32 + ty + j * 8;
    t[ty + j * 8][tx] = qkv[(size_t)(b * 2048 + s) * 6144 + 4096 + h * 128 + dh];
  }
  __syncthreads();
  int s2 = blockIdx.y * 32 + tx;
#pragma unroll
  for (int j = 0; j < 4; ++j) {
    int dh2 = blockIdx.x * 32 + ty + j * 8;
    Vt[(size_t)(bh * 128 + dh2) * 2048 + s2] = t[tx][ty + j * 8];
  }
}

// ------------- bf16 GEMM: C[M][N] = A[M][K] * B[N][K]^T  (m97 structure, 0 conflicts) ----
// OUTMODE: 0 = fp32, 1 = bf16
template <typename CT, int OUTMODE>
__global__ __launch_bounds__(256) void btgemm_k(const u16* __restrict__ A0,
                                                const u16* __restrict__ B0,
                                                CT* __restrict__ C,
                                                int M, int N, int K) {
  __shared__ u16 As[128 * 64];
  __shared__ u16 Bs[128 * 64];
  int nnt = N >> 7;
  int bid = blockIdx.x;
  int nwg = gridDim.x;
  if ((nwg & 7) == 0) { int q = nwg >> 3; bid = (bid & 7) * q + (bid >> 3); }  // XCD swizzle
  int mt = bid / nnt, nt = bid - mt * nnt;
  int tid = threadIdx.x, wave = tid >> 6, lane = tid & 63;
  int l15 = lane & 15, l4 = lane >> 4;
  int wr = wave >> 1, wc = wave & 1;
  int sr = lane >> 3, sc = lane & 7;
  int gsl = (sc ^ sr) * 8;  // pre-swizzled source slot (elements)

  const u16* Ag = A0 + (size_t)(mt * 128 + wave * 32 + sr) * K + gsl;
  const u16* Bg = B0 + (size_t)(nt * 128 + wave * 32 + sr) * K + gsl;
  u16* Asw = As + wave * 32 * 64;
  u16* Bsw = Bs + wave * 32 * 64;

  f32x4 acc[4][4];
#pragma unroll
  for (int i = 0; i < 4; ++i)
#pragma unroll
    for (int j = 0; j < 4; ++j) acc[i][j] = f32x4{0.f, 0.f, 0.f, 0.f};

  for (int kt = 0; kt < K; kt += 64) {
#pragma unroll
    for (int i = 0; i < 4; ++i) {
      gload16(Ag + kt + i * 8 * K, Asw + i * 512);
      gload16(Bg + kt + i * 8 * K, Bsw + i * 512);
    }
    __syncthreads();
#pragma unroll
    for (int kk = 0; kk < 2; ++kk) {
      s16x8 af[4], bfr[4];
#pragma unroll
      for (int mf = 0; mf < 4; ++mf) {
        int row = wr * 64 + mf * 16 + l15;
        int sl = ((kk * 4 + l4) ^ (row & 7)) * 8;
        af[mf] = *(const s16x8*)(As + row * 64 + sl);
      }
#pragma unroll
      for (int nf = 0; nf < 4; ++nf) {
        int row = wc * 64 + nf * 16 + l15;
        int sl = ((kk * 4 + l4) ^ (row & 7)) * 8;
        bfr[nf] = *(const s16x8*)(Bs + row * 64 + sl);
      }
#pragma unroll
      for (int mf = 0; mf < 4; ++mf)
#pragma unroll
        for (int nf = 0; nf < 4; ++nf)
          acc[mf][nf] = __builtin_amdgcn_mfma_f32_16x16x32_bf16(af[mf], bfr[nf], acc[mf][nf], 0, 0, 0);
    }
    __syncthreads();
  }

  int crow = mt * 128 + wr * 64 + l4 * 4;
  int ccol = nt * 128 + wc * 64 + l15;
#pragma unroll
  for (int mf = 0; mf < 4; ++mf)
#pragma unroll
    for (int nf = 0; nf < 4; ++nf)
#pragma unroll
      for (int r = 0; r < 4; ++r) {
        size_t idx = (size_t)(crow + mf * 16 + r) * N + (ccol + nf * 16);
        float v = acc[mf][nf][r];
        if constexpr (OUTMODE == 0) C[idx] = v; else C[idx] = f2bf(v);
      }
}

// ------------- MFMA flash attention v6 (unchanged from round 8, green) -------------
__global__ __launch_bounds__(256) void attn6_k(const u16* __restrict__ qkv,
                                               const u16* __restrict__ Vt,
                                               u16* __restrict__ outl) {
  __shared__ u16 Ks[64 * 128];    // [kv][d], XOR-swizzled 16B slots
  __shared__ u16 Vs[128 * 64];    // [dh][kv], XOR-swizzled
  __shared__ u16 Ps2[4 * 32 * 64];// per-wave P[q][kv], XOR-swizzled 16B granules

  int bid = blockIdx.x;
  int xcd = bid & 7, slot = bid >> 3;  // bh->XCD locality
  int bh = xcd * 8 + (slot >> 4), qb = slot & 15;
  int b = bh >> 4, h = bh & 15;
  int tid = threadIdx.x, wave = tid >> 6, lane = tid & 63;
  int l15 = lane & 15, l4 = lane >> 4;
  int q0 = qb * 128 + wave * 32;
  const float ksc = 0.12751743f;  // log2(e)/sqrt(128)

  s16x8 qf[2][4];
#pragma unroll
  for (int mf = 0; mf < 2; ++mf)
#pragma unroll
    for (int kf = 0; kf < 4; ++kf)
      qf[mf][kf] = *(const s16x8*)(qkv + (size_t)(b * 2048 + q0 + mf * 16 + l15) * 6144 +
                                   h * 128 + kf * 32 + l4 * 8);

  f32x4 po[2][8];
  float mrun[2], lrun[2];
#pragma unroll
  for (int mf = 0; mf < 2; ++mf) {
#pragma unroll
    for (int n2 = 0; n2 < 8; ++n2) po[mf][n2] = f32x4{0.f, 0.f, 0.f, 0.f};
    mrun[mf] = -1e30f; lrun[mf] = 0.f;
  }

  char* PsW = (char*)(Ps2 + wave * 2048);

  int krow_b = wave * 16;
  int vrow_b = wave * 32;
  int kj = lane & 15;
  int vj = lane & 7;

  s16x8 kr[4], vr[4];
#define GLOAD_TILE(kv0)                                                                  \
  _Pragma("unroll") for (int i = 0; i < 4; ++i) {                                        \
    int row = krow_b + i * 4 + (lane >> 4);                                              \
    kr[i] = *(const s16x8*)(qkv + (size_t)(b * 2048 + (kv0) + row) * 6144 + 2048 +       \
                            h * 128 + kj * 8);                                           \
    int row2 = vrow_b + i * 8 + (lane >> 3);                                             \
    vr[i] = *(const s16x8*)(Vt + (size_t)(bh * 128 + row2) * 2048 + (kv0) + vj * 8);     \
  }

  GLOAD_TILE(0)

  for (int t = 0; t < 32; ++t) {
    __syncthreads();
#pragma unroll
    for (int i = 0; i < 4; ++i) {
      int row = krow_b + i * 4 + (lane >> 4);
      *(s16x8*)(Ks + row * 128 + ((kj ^ (row & 7)) * 8)) = kr[i];
      int row2 = vrow_b + i * 8 + (lane >> 3);
      *(s16x8*)(Vs + row2 * 64 + ((vj ^ (row2 & 7)) * 8)) = vr[i];
    }
    __syncthreads();
    if (t < 31) GLOAD_TILE((t + 1) * 64)

    // ---- QK^T (swapped: A=K, B=Q) ----
    f32x4 sa[2][4];
#pragma unroll
    for (int mf = 0; mf < 2; ++mf)
#pragma unroll
      for (int nf = 0; nf < 4; ++nf) sa[mf][nf] = f32x4{0.f, 0.f, 0.f, 0.f};
    __builtin_amdgcn_s_setprio(1);
#pragma unroll
    for (int kf = 0; kf < 4; ++kf) {
      s16x8 kb[4];
#pragma unroll
      for (int nf = 0; nf < 4; ++nf) {
        int row = nf * 16 + l15;
        int sl = ((kf * 4 + l4) ^ (row & 7)) * 8;
        kb[nf] = *(const s16x8*)(Ks + row * 128 + sl);
      }
#pragma unroll
      for (int mf = 0; mf < 2; ++mf)
#pragma unroll
        for (int nf = 0; nf < 4; ++nf)
          sa[mf][nf] = __builtin_amdgcn_mfma_f32_16x16x32_bf16(kb[nf], qf[mf][kf], sa[mf][nf], 0, 0, 0);
    }
    __builtin_amdgcn_s_setprio(0);

    // ---- in-register online softmax ----
#pragma unroll
    for (int mf = 0; mf < 2; ++mf) {
      float m01 = fmaxf(fmaxf(sa[mf][0][0], sa[mf][0][1]), fmaxf(sa[mf][0][2], sa[mf][0][3]));
      float m23 = fmaxf(fmaxf(sa[mf][1][0], sa[mf][1][1]), fmaxf(sa[mf][1][2], sa[mf][1][3]));
      float m45 = fmaxf(fmaxf(sa[mf][2][0], sa[mf][2][1]), fmaxf(sa[mf][2][2], sa[mf][2][3]));
      float m67 = fmaxf(fmaxf(sa[mf][3][0], sa[mf][3][1]), fmaxf(sa[mf][3][2], sa[mf][3][3]));
      float pmax = fmaxf(fmaxf(m01, m23), fmaxf(m45, m67));
      pmax = fmaxf(pmax, __shfl_xor(pmax, 16, 64));
      pmax = fmaxf(pmax, __shfl_xor(pmax, 32, 64));
      if (!__all((pmax - mrun[mf]) * ksc <= 8.0f)) {  // T13 defer-max
        float mnew = fmaxf(mrun[mf], pmax);
        float fsc = exp2f((mrun[mf] - mnew) * ksc);
        lrun[mf] *= fsc;
#pragma unroll
        for (int n2 = 0; n2 < 8; ++n2)
#pragma unroll
          for (int r = 0; r < 4; ++r) po[mf][n2][r] *= fsc;
        mrun[mf] = mnew;
      }
      int row = mf * 16 + l15;
      int swz = (row & 7) << 4;
      float ssum = 0.f;
#pragma unroll
      for (int nf = 0; nf < 4; ++nf) {
        float p0 = exp2f((sa[mf][nf][0] - mrun[mf]) * ksc);
        float p1 = exp2f((sa[mf][nf][1] - mrun[mf]) * ksc);
        float p2 = exp2f((sa[mf][nf][2] - mrun[mf]) * ksc);
        float p3 = exp2f((sa[mf][nf][3] - mrun[mf]) * ksc);
        ssum += (p0 + p1) + (p2 + p3);
        u16x4 w;
        w.x = f2bf(p0); w.y = f2bf(p1); w.z = f2bf(p2); w.w = f2bf(p3);
        *(u16x4*)(PsW + row * 128 + (((nf * 4 + l4) * 8) ^ swz)) = w;
      }
      ssum += __shfl_xor(ssum, 16, 64);
      ssum += __shfl_xor(ssum, 32, 64);
      lrun[mf] += ssum;
    }

    // ---- P fragments ----
    s16x8 pb[2][2];
#pragma unroll
    for (int mf = 0; mf < 2; ++mf) {
      int row = mf * 16 + l15;
      int swz = (row & 7) << 4;
#pragma unroll
      for (int k2 = 0; k2 < 2; ++k2)
        pb[mf][k2] = *(const s16x8*)(PsW + row * 128 + ((k2 * 64 + l4 * 16) ^ swz));
    }

    // ---- PV (A=V^T, B=P) ----
    __builtin_amdgcn_s_setprio(1);
#pragma unroll
    for (int n2 = 0; n2 < 8; ++n2) {
#pragma unroll
      for (int k2 = 0; k2 < 2; ++k2) {
        int row = n2 * 16 + l15;
        int sl = ((k2 * 4 + l4) ^ (row & 7)) * 8;
        s16x8 vb = *(const s16x8*)(Vs + row * 64 + sl);
#pragma unroll
        for (int mf = 0; mf < 2; ++mf)
          po[mf][n2] = __builtin_amdgcn_mfma_f32_16x16x32_bf16(vb, pb[mf][k2], po[mf][n2], 0, 0, 0);
      }
    }
    __builtin_amdgcn_s_setprio(0);
  }
#undef GLOAD_TILE

  // epilogue
#pragma unroll
  for (int mf = 0; mf < 2; ++mf) {
    float inv = 1.0f / lrun[mf];
#pragma unroll
    for (int n2 = 0; n2 < 8; ++n2) {
      u16x4 w;
      w.x = f2bf(po[mf][n2][0] * inv);
      w.y = f2bf(po[mf][n2][1] * inv);
      w.z = f2bf(po[mf][n2][2] * inv);
      w.w = f2bf(po[mf][n2][3] * inv);
      *(u16x4*)(outl + (size_t)(b * 2048 + q0 + mf * 16 + l15) * 2048 + h * 128 +
                n2 * 16 + l4 * 4) = w;
    }
  }
}

extern "C" void kernel_launch(void* const* d_in, const int* in_sizes, int n_in,
                              void* d_out, int out_size, void* d_ws, size_t ws_size,
                              hipStream_t stream) {
  (void)in_sizes; (void)n_in;
  const float* hs  = (const float*)d_in[0];
  const float* Wq  = (const float*)d_in[1];
  const float* Wkd = (const float*)d_in[2];
  const float* Wvd = (const float*)d_in[3];
  const float* Wku = (const float*)d_in[4];
  const float* Wo  = (const float*)d_in[5];
  float* out = (float*)d_out;
  char* ws = (char*)d_ws;

  // ws sentinel: need 192 MiB
  if (ws_size < 201326592ull) {
    fill_k<<<4096, 256, 0, stream>>>(out, out_size, 1e9f);
    return;
  }

  // workspace layout (bytes), total 192 MiB, time-multiplexed:
  //  [0,        25.17M) W3  (live: cvtall -> qkv GEMM)
  //  [25.17M,   33.55M) WcH (live: Wc GEMM -> final GEMM)
  //  [33.55M,   67.11M) hsB (live -> qkv GEMM); then outl (attn -> final GEMM)
  //  [67.11M,  167.77M) qkv
  //  [167.77M, 201.33M) WoB|WkuT (live: cvtall/cvtT -> Wc GEMM); then Vt (vtrans -> attn)
  u16* W3   = (u16*)(ws);
  u16* WcH  = (u16*)(ws + 25165824);
  u16* hsB  = (u16*)(ws + 33554432);
  u16* outl = (u16*)(ws + 33554432);
  u16* qkv  = (u16*)(ws + 67108864);
  u16* WoB  = (u16*)(ws + 167772160);
  u16* WkuT = (u16*)(ws + 176160768);
  u16* Vt   = (u16*)(ws + 167772160);

  // all fp32->bf16 converts in one launch
  cvtall_k<<<32768, 256, 0, stream>>>(hs, Wq, Wkd, Wvd, Wo, hsB, W3, WoB);
  cvtT_k<<<dim3(64, 64), dim3(32, 8), 0, stream>>>(Wku, WkuT);

  // qkv = hsB @ [Wq|Wk_down|Wv_down]^T
  btgemm_k<u16, 1><<<3072, 256, 0, stream>>>(hsB, W3, qkv, 8192, 6144, 2048);

  // Wc = Wo @ Wk_up  (single bf16 pass)
  btgemm_k<u16, 1><<<256, 256, 0, stream>>>(WoB, WkuT, WcH, 2048, 2048, 2048);

  vtrans_k<<<dim3(4, 64, 64), dim3(32, 8), 0, stream>>>(qkv, Vt);
  attn6_k<<<1024, 256, 0, stream>>>(qkv, Vt, outl);

  // out = out_lat @ Wc^T  (single pass, fp32 out)
  btgemm_k<float, 0><<<1024, 256, 0, stream>>>(outl, WcH, out, 8192, 2048, 2048);
}

// Round 10
// 674.783 us; speedup vs baseline: 1.6944x; 1.0549x over previous
//
#include <hip/hip_runtime.h>
#include <hip/hip_bf16.h>
#include <stdint.h>

typedef unsigned short u16;
typedef __attribute__((ext_vector_type(4))) float f32x4;
typedef __attribute__((ext_vector_type(8))) short s16x8;
typedef __attribute__((ext_vector_type(4))) u16 u16x4;

__device__ __forceinline__ u16 f2bf(float x) {
  union { float f; uint32_t u; } v; v.f = x;
  uint32_t r = v.u + 0x7FFFu + ((v.u >> 16) & 1u);
  return (u16)(r >> 16);
}
// compiler-recognized scalar cast (emits native cvt; pairs into cvt_pk) [m240]
__device__ __forceinline__ u16 f2bfh(float x) {
  __hip_bfloat16 h = __float2bfloat16(x);
  u16 r; __builtin_memcpy(&r, &h, 2); return r;
}

__device__ __forceinline__ void gload16(const void* g, const void* l) {
  __builtin_amdgcn_global_load_lds((const __attribute__((address_space(1))) void*)g,
                                   (__attribute__((address_space(3))) void*)l,
                                   16, 0, 0);
}

__global__ void fill_k(float* out, int n, float v) {
  for (int i = blockIdx.x * blockDim.x + threadIdx.x; i < n; i += gridDim.x * blockDim.x)
    out[i] = v;
}

// ------------- fused fp32 -> bf16 convert for hs, Wq, Wkd, Wvd, Wo (one launch) -------------
__global__ void cvtall_k(const float* __restrict__ hs, const float* __restrict__ Wq,
                         const float* __restrict__ Wkd, const float* __restrict__ Wvd,
                         const float* __restrict__ Wo,
                         u16* __restrict__ hsB, u16* __restrict__ W3, u16* __restrict__ WoB) {
  int i = blockIdx.x * blockDim.x + threadIdx.x;  // f32x4 units, total 8388608
  const float* src; u16* dst; int off;
  if (i < 4194304)      { src = hs;  dst = hsB;          off = i; }
  else if (i < 5242880) { src = Wq;  dst = W3;           off = i - 4194304; }
  else if (i < 6291456) { src = Wkd; dst = W3 + 4194304; off = i - 5242880; }
  else if (i < 7340032) { src = Wvd; dst = W3 + 8388608; off = i - 6291456; }
  else                  { src = Wo;  dst = WoB;          off = i - 7340032; }
  f32x4 v = ((const f32x4*)src)[off];
  u16x4 o;
  o.x = f2bf(v.x); o.y = f2bf(v.y); o.z = f2bf(v.z); o.w = f2bf(v.w);
  ((u16x4*)dst)[off] = o;
}

// ------------- fp32 [2048][2048] -> bf16 transposed -------------
__global__ void cvtT_k(const float* __restrict__ in, u16* __restrict__ out) {
  __shared__ float t[32][33];
  int tx = threadIdx.x, ty = threadIdx.y;
  int c = blockIdx.x * 32 + tx;
#pragma unroll
  for (int j = 0; j < 4; ++j) {
    int r = blockIdx.y * 32 + ty + j * 8;
    t[ty + j * 8][tx] = in[(size_t)r * 2048 + c];
  }
  __syncthreads();
  int c2 = blockIdx.y * 32 + tx;
#pragma unroll
  for (int j = 0; j < 4; ++j) {
    int r2 = blockIdx.x * 32 + ty + j * 8;
    out[(size_t)r2 * 2048 + c2] = f2bf(t[tx][ty + j * 8]);
  }
}

// ------------- bf16 GEMM: C[M][N] = A[M][K] * B[N][K]^T  (m97 structure) ----
// OUTMODE: 0 = fp32, 1 = bf16.  VOUT: columns >= 4096 are V -> store transposed to Vt
// (Vt[(b*16+h)*128+dh][s]) instead of C; fuses the old vtrans kernel into the epilogue.
template <typename CT, int OUTMODE, bool VOUT>
__global__ __launch_bounds__(256) void btgemm_k(const u16* __restrict__ A0,
                                                const u16* __restrict__ B0,
                                                CT* __restrict__ C,
                                                u16* __restrict__ Vt,
                                                int M, int N, int K) {
  __shared__ u16 As[128 * 64];
  __shared__ u16 Bs[128 * 64];
  int nnt = N >> 7;
  int bid = blockIdx.x;
  int nwg = gridDim.x;
  if ((nwg & 7) == 0) { int q = nwg >> 3; bid = (bid & 7) * q + (bid >> 3); }  // XCD swizzle
  int mt = bid / nnt, nt = bid - mt * nnt;
  int tid = threadIdx.x, wave = tid >> 6, lane = tid & 63;
  int l15 = lane & 15, l4 = lane >> 4;
  int wr = wave >> 1, wc = wave & 1;
  int sr = lane >> 3, sc = lane & 7;
  int gsl = (sc ^ sr) * 8;  // pre-swizzled source slot (elements)

  const u16* Ag = A0 + (size_t)(mt * 128 + wave * 32 + sr) * K + gsl;
  const u16* Bg = B0 + (size_t)(nt * 128 + wave * 32 + sr) * K + gsl;
  u16* Asw = As + wave * 32 * 64;
  u16* Bsw = Bs + wave * 32 * 64;

  f32x4 acc[4][4];
#pragma unroll
  for (int i = 0; i < 4; ++i)
#pragma unroll
    for (int j = 0; j < 4; ++j) acc[i][j] = f32x4{0.f, 0.f, 0.f, 0.f};

  for (int kt = 0; kt < K; kt += 64) {
#pragma unroll
    for (int i = 0; i < 4; ++i) {
      gload16(Ag + kt + i * 8 * K, Asw + i * 512);
      gload16(Bg + kt + i * 8 * K, Bsw + i * 512);
    }
    __syncthreads();
#pragma unroll
    for (int kk = 0; kk < 2; ++kk) {
      s16x8 af[4], bfr[4];
#pragma unroll
      for (int mf = 0; mf < 4; ++mf) {
        int row = wr * 64 + mf * 16 + l15;
        int sl = ((kk * 4 + l4) ^ (row & 7)) * 8;
        af[mf] = *(const s16x8*)(As + row * 64 + sl);
      }
#pragma unroll
      for (int nf = 0; nf < 4; ++nf) {
        int row = wc * 64 + nf * 16 + l15;
        int sl = ((kk * 4 + l4) ^ (row & 7)) * 8;
        bfr[nf] = *(const s16x8*)(Bs + row * 64 + sl);
      }
#pragma unroll
      for (int mf = 0; mf < 4; ++mf)
#pragma unroll
        for (int nf = 0; nf < 4; ++nf)
          acc[mf][nf] = __builtin_amdgcn_mfma_f32_16x16x32_bf16(af[mf], bfr[nf], acc[mf][nf], 0, 0, 0);
    }
    __syncthreads();
  }

  int crow = mt * 128 + wr * 64 + l4 * 4;
  int ccol = nt * 128 + wc * 64 + l15;
#pragma unroll
  for (int mf = 0; mf < 4; ++mf)
#pragma unroll
    for (int nf = 0; nf < 4; ++nf) {
      int col = ccol + nf * 16;
      int row0 = crow + mf * 16;
      if (VOUT && col >= 4096) {
        // transposed V store: Vt[(b*16+h)*128 + dh][s0..s0+3]
        int h = (col - 4096) >> 7, dh = (col - 4096) & 127;
        int b = row0 >> 11, s0 = row0 & 2047;
        u16x4 w;
        w.x = f2bfh(acc[mf][nf][0]); w.y = f2bfh(acc[mf][nf][1]);
        w.z = f2bfh(acc[mf][nf][2]); w.w = f2bfh(acc[mf][nf][3]);
        *(u16x4*)(Vt + ((size_t)((b << 4) + h) * 128 + dh) * 2048 + s0) = w;
      } else {
#pragma unroll
        for (int r = 0; r < 4; ++r) {
          size_t idx = (size_t)(row0 + r) * N + col;
          float v = acc[mf][nf][r];
          if constexpr (OUTMODE == 0) C[idx] = v; else C[idx] = f2bfh(v);
        }
      }
    }
}

// ------------- MFMA flash attention v7: v6 + scaled-max FMA exp + native casts -------------
__global__ __launch_bounds__(256) void attn7_k(const u16* __restrict__ qkv,
                                               const u16* __restrict__ Vt,
                                               u16* __restrict__ outl) {
  __shared__ u16 Ks[64 * 128];    // [kv][d], XOR-swizzled 16B slots
  __shared__ u16 Vs[128 * 64];    // [dh][kv], XOR-swizzled
  __shared__ u16 Ps2[4 * 32 * 64];// per-wave P[q][kv], XOR-swizzled 16B granules

  int bid = blockIdx.x;
  int xcd = bid & 7, slot = bid >> 3;  // bh->XCD locality
  int bh = xcd * 8 + (slot >> 4), qb = slot & 15;
  int b = bh >> 4, h = bh & 15;
  int tid = threadIdx.x, wave = tid >> 6, lane = tid & 63;
  int l15 = lane & 15, l4 = lane >> 4;
  int q0 = qb * 128 + wave * 32;
  const float ksc = 0.12751743f;  // log2(e)/sqrt(128)

  s16x8 qf[2][4];
#pragma unroll
  for (int mf = 0; mf < 2; ++mf)
#pragma unroll
    for (int kf = 0; kf < 4; ++kf)
      qf[mf][kf] = *(const s16x8*)(qkv + (size_t)(b * 2048 + q0 + mf * 16 + l15) * 6144 +
                                   h * 128 + kf * 32 + l4 * 8);

  f32x4 po[2][8];
  float smrun[2], lrun[2];  // smrun tracks m*ksc (log2 units)
#pragma unroll
  for (int mf = 0; mf < 2; ++mf) {
#pragma unroll
    for (int n2 = 0; n2 < 8; ++n2) po[mf][n2] = f32x4{0.f, 0.f, 0.f, 0.f};
    smrun[mf] = -1e30f; lrun[mf] = 0.f;
  }

  char* PsW = (char*)(Ps2 + wave * 2048);

  int krow_b = wave * 16;
  int vrow_b = wave * 32;
  int kj = lane & 15;
  int vj = lane & 7;

  s16x8 kr[4], vr[4];
#define GLOAD_TILE(kv0)                                                                  \
  _Pragma("unroll") for (int i = 0; i < 4; ++i) {                                        \
    int row = krow_b + i * 4 + (lane >> 4);                                              \
    kr[i] = *(const s16x8*)(qkv + (size_t)(b * 2048 + (kv0) + row) * 6144 + 2048 +       \
                            h * 128 + kj * 8);                                           \
    int row2 = vrow_b + i * 8 + (lane >> 3);                                             \
    vr[i] = *(const s16x8*)(Vt + (size_t)(bh * 128 + row2) * 2048 + (kv0) + vj * 8);     \
  }

  GLOAD_TILE(0)

  for (int t = 0; t < 32; ++t) {
    __syncthreads();
#pragma unroll
    for (int i = 0; i < 4; ++i) {
      int row = krow_b + i * 4 + (lane >> 4);
      *(s16x8*)(Ks + row * 128 + ((kj ^ (row & 7)) * 8)) = kr[i];
      int row2 = vrow_b + i * 8 + (lane >> 3);
      *(s16x8*)(Vs + row2 * 64 + ((vj ^ (row2 & 7)) * 8)) = vr[i];
    }
    __syncthreads();
    if (t < 31) GLOAD_TILE((t + 1) * 64)

    // ---- QK^T (swapped: A=K, B=Q) ----
    f32x4 sa[2][4];
#pragma unroll
    for (int mf = 0; mf < 2; ++mf)
#pragma unroll
      for (int nf = 0; nf < 4; ++nf) sa[mf][nf] = f32x4{0.f, 0.f, 0.f, 0.f};
    __builtin_amdgcn_s_setprio(1);
#pragma unroll
    for (int kf = 0; kf < 4; ++kf) {
      s16x8 kb[4];
#pragma unroll
      for (int nf = 0; nf < 4; ++nf) {
        int row = nf * 16 + l15;
        int sl = ((kf * 4 + l4) ^ (row & 7)) * 8;
        kb[nf] = *(const s16x8*)(Ks + row * 128 + sl);
      }
#pragma unroll
      for (int mf = 0; mf < 2; ++mf)
#pragma unroll
        for (int nf = 0; nf < 4; ++nf)
          sa[mf][nf] = __builtin_amdgcn_mfma_f32_16x16x32_bf16(kb[nf], qf[mf][kf], sa[mf][nf], 0, 0, 0);
    }
    __builtin_amdgcn_s_setprio(0);

    // ---- in-register online softmax (scaled-units running max) ----
#pragma unroll
    for (int mf = 0; mf < 2; ++mf) {
      float m01 = fmaxf(fmaxf(sa[mf][0][0], sa[mf][0][1]), fmaxf(sa[mf][0][2], sa[mf][0][3]));
      float m23 = fmaxf(fmaxf(sa[mf][1][0], sa[mf][1][1]), fmaxf(sa[mf][1][2], sa[mf][1][3]));
      float m45 = fmaxf(fmaxf(sa[mf][2][0], sa[mf][2][1]), fmaxf(sa[mf][2][2], sa[mf][2][3]));
      float m67 = fmaxf(fmaxf(sa[mf][3][0], sa[mf][3][1]), fmaxf(sa[mf][3][2], sa[mf][3][3]));
      float pmax = fmaxf(fmaxf(m01, m23), fmaxf(m45, m67));
      pmax = fmaxf(pmax, __shfl_xor(pmax, 16, 64));
      pmax = fmaxf(pmax, __shfl_xor(pmax, 32, 64));
      float smax = pmax * ksc;
      if (!__all(smax - smrun[mf] <= 8.0f)) {  // T13 defer-max
        float mnew = fmaxf(smrun[mf], smax);
        float fsc = exp2f(smrun[mf] - mnew);
        lrun[mf] *= fsc;
#pragma unroll
        for (int n2 = 0; n2 < 8; ++n2)
#pragma unroll
          for (int r = 0; r < 4; ++r) po[mf][n2][r] *= fsc;
        smrun[mf] = mnew;
      }
      int row = mf * 16 + l15;
      int swz = (row & 7) << 4;
      float ssum = 0.f;
#pragma unroll
      for (int nf = 0; nf < 4; ++nf) {
        float p0 = exp2f(fmaf(sa[mf][nf][0], ksc, -smrun[mf]));
        float p1 = exp2f(fmaf(sa[mf][nf][1], ksc, -smrun[mf]));
        float p2 = exp2f(fmaf(sa[mf][nf][2], ksc, -smrun[mf]));
        float p3 = exp2f(fmaf(sa[mf][nf][3], ksc, -smrun[mf]));
        ssum += (p0 + p1) + (p2 + p3);
        u16x4 w;
        w.x = f2bfh(p0); w.y = f2bfh(p1); w.z = f2bfh(p2); w.w = f2bfh(p3);
        *(u16x4*)(PsW + row * 128 + (((nf * 4 + l4) * 8) ^ swz)) = w;
      }
      ssum += __shfl_xor(ssum, 16, 64);
      ssum += __shfl_xor(ssum, 32, 64);
      lrun[mf] += ssum;
    }

    // ---- P fragments ----
    s16x8 pb[2][2];
#pragma unroll
    for (int mf = 0; mf < 2; ++mf) {
      int row = mf * 16 + l15;
      int swz = (row & 7) << 4;
#pragma unroll
      for (int k2 = 0; k2 < 2; ++k2)
        pb[mf][k2] = *(const s16x8*)(PsW + row * 128 + ((k2 * 64 + l4 * 16) ^ swz));
    }

    // ---- PV (A=V^T, B=P) ----
    __builtin_amdgcn_s_setprio(1);
#pragma unroll
    for (int n2 = 0; n2 < 8; ++n2) {
#pragma unroll
      for (int k2 = 0; k2 < 2; ++k2) {
        int row = n2 * 16 + l15;
        int sl = ((k2 * 4 + l4) ^ (row & 7)) * 8;
        s16x8 vb = *(const s16x8*)(Vs + row * 64 + sl);
#pragma unroll
        for (int mf = 0; mf < 2; ++mf)
          po[mf][n2] = __builtin_amdgcn_mfma_f32_16x16x32_bf16(vb, pb[mf][k2], po[mf][n2], 0, 0, 0);
      }
    }
    __builtin_amdgcn_s_setprio(0);
  }
#undef GLOAD_TILE

  // epilogue
#pragma unroll
  for (int mf = 0; mf < 2; ++mf) {
    float inv = 1.0f / lrun[mf];
#pragma unroll
    for (int n2 = 0; n2 < 8; ++n2) {
      u16x4 w;
      w.x = f2bfh(po[mf][n2][0] * inv);
      w.y = f2bfh(po[mf][n2][1] * inv);
      w.z = f2bfh(po[mf][n2][2] * inv);
      w.w = f2bfh(po[mf][n2][3] * inv);
      *(u16x4*)(outl + (size_t)(b * 2048 + q0 + mf * 16 + l15) * 2048 + h * 128 +
                n2 * 16 + l4 * 4) = w;
    }
  }
}

extern "C" void kernel_launch(void* const* d_in, const int* in_sizes, int n_in,
                              void* d_out, int out_size, void* d_ws, size_t ws_size,
                              hipStream_t stream) {
  (void)in_sizes; (void)n_in;
  const float* hs  = (const float*)d_in[0];
  const float* Wq  = (const float*)d_in[1];
  const float* Wkd = (const float*)d_in[2];
  const float* Wvd = (const float*)d_in[3];
  const float* Wku = (const float*)d_in[4];
  const float* Wo  = (const float*)d_in[5];
  float* out = (float*)d_out;
  char* ws = (char*)d_ws;

  // ws sentinel: need 192 MiB
  if (ws_size < 201326592ull) {
    fill_k<<<4096, 256, 0, stream>>>(out, out_size, 1e9f);
    return;
  }

  // workspace layout (192 MiB), time-multiplexed:
  //  [0,        25.17M) W3   (cvtall -> qkv GEMM)
  //  [25.17M,   33.55M) WcH  (Wc GEMM -> final GEMM)
  //  [33.55M,   67.11M) hsB  (cvtall -> qkv GEMM); then outl (attn -> final GEMM)
  //  [67.11M,  167.77M) qkv  (q|k cols only; v cols unwritten)
  //  [167.77M, 201.33M) WoB|WkuT (cvtall/cvtT -> Wc GEMM); then Vt (qkv GEMM -> attn)
  u16* W3   = (u16*)(ws);
  u16* WcH  = (u16*)(ws + 25165824);
  u16* hsB  = (u16*)(ws + 33554432);
  u16* outl = (u16*)(ws + 33554432);
  u16* qkv  = (u16*)(ws + 67108864);
  u16* WoB  = (u16*)(ws + 167772160);
  u16* WkuT = (u16*)(ws + 176160768);
  u16* Vt   = (u16*)(ws + 167772160);

  cvtall_k<<<32768, 256, 0, stream>>>(hs, Wq, Wkd, Wvd, Wo, hsB, W3, WoB);
  cvtT_k<<<dim3(64, 64), dim3(32, 8), 0, stream>>>(Wku, WkuT);

  // Wc = Wo @ Wk_up  (must precede qkv GEMM: Vt overwrites WoB/WkuT region)
  btgemm_k<u16, 1, false><<<256, 256, 0, stream>>>(WoB, WkuT, WcH, nullptr, 2048, 2048, 2048);

  // qkv = hsB @ [Wq|Wk_down|Wv_down]^T ; v columns routed transposed into Vt
  btgemm_k<u16, 1, true><<<3072, 256, 0, stream>>>(hsB, W3, qkv, Vt, 8192, 6144, 2048);

  attn7_k<<<1024, 256, 0, stream>>>(qkv, Vt, outl);

  // out = out_lat @ Wc^T  (fp32 out)
  btgemm_k<float, 0, false><<<1024, 256, 0, stream>>>(outl, WcH, out, nullptr, 8192, 2048, 2048);
}

// Round 11
// 591.906 us; speedup vs baseline: 1.9316x; 1.1400x over previous
//
#include <hip/hip_runtime.h>
#include <hip/hip_bf16.h>
#include <stdint.h>

typedef unsigned short u16;
typedef __attribute__((ext_vector_type(4))) float f32x4;
typedef __attribute__((ext_vector_type(8))) short s16x8;
typedef __attribute__((ext_vector_type(4))) u16 u16x4;

__device__ __forceinline__ u16 f2bf(float x) {
  union { float f; uint32_t u; } v; v.f = x;
  uint32_t r = v.u + 0x7FFFu + ((v.u >> 16) & 1u);
  return (u16)(r >> 16);
}
// compiler-recognized scalar cast (emits native cvt; pairs into cvt_pk) [m240]
__device__ __forceinline__ u16 f2bfh(float x) {
  __hip_bfloat16 h = __float2bfloat16(x);
  u16 r; __builtin_memcpy(&r, &h, 2); return r;
}

__device__ __forceinline__ void gload16(const void* g, const void* l) {
  __builtin_amdgcn_global_load_lds((const __attribute__((address_space(1))) void*)g,
                                   (__attribute__((address_space(3))) void*)l,
                                   16, 0, 0);
}

__global__ void fill_k(float* out, int n, float v) {
  for (int i = blockIdx.x * blockDim.x + threadIdx.x; i < n; i += gridDim.x * blockDim.x)
    out[i] = v;
}

// ------------- fused fp32 -> bf16 convert for hs, Wq, Wkd, Wvd, Wo (one launch) -------------
__global__ void cvtall_k(const float* __restrict__ hs, const float* __restrict__ Wq,
                         const float* __restrict__ Wkd, const float* __restrict__ Wvd,
                         const float* __restrict__ Wo,
                         u16* __restrict__ hsB, u16* __restrict__ W3, u16* __restrict__ WoB) {
  int i = blockIdx.x * blockDim.x + threadIdx.x;  // f32x4 units, total 8388608
  const float* src; u16* dst; int off;
  if (i < 4194304)      { src = hs;  dst = hsB;          off = i; }
  else if (i < 5242880) { src = Wq;  dst = W3;           off = i - 4194304; }
  else if (i < 6291456) { src = Wkd; dst = W3 + 4194304; off = i - 5242880; }
  else if (i < 7340032) { src = Wvd; dst = W3 + 8388608; off = i - 6291456; }
  else                  { src = Wo;  dst = WoB;          off = i - 7340032; }
  f32x4 v = ((const f32x4*)src)[off];
  u16x4 o;
  o.x = f2bf(v.x); o.y = f2bf(v.y); o.z = f2bf(v.z); o.w = f2bf(v.w);
  ((u16x4*)dst)[off] = o;
}

// ------------- fp32 [2048][2048] -> bf16 transposed -------------
__global__ void cvtT_k(const float* __restrict__ in, u16* __restrict__ out) {
  __shared__ float t[32][33];
  int tx = threadIdx.x, ty = threadIdx.y;
  int c = blockIdx.x * 32 + tx;
#pragma unroll
  for (int j = 0; j < 4; ++j) {
    int r = blockIdx.y * 32 + ty + j * 8;
    t[ty + j * 8][tx] = in[(size_t)r * 2048 + c];
  }
  __syncthreads();
  int c2 = blockIdx.y * 32 + tx;
#pragma unroll
  for (int j = 0; j < 4; ++j) {
    int r2 = blockIdx.x * 32 + ty + j * 8;
    out[(size_t)r2 * 2048 + c2] = f2bf(t[tx][ty + j * 8]);
  }
}

// ------------- bf16 GEMM: C[M][N] = A[M][K] * B[N][K]^T  (m97 structure) ----
// OUTMODE: 0 = fp32, 1 = bf16.  VOUT: columns >= 4096 are V -> store transposed to Vt
template <typename CT, int OUTMODE, bool VOUT>
__global__ __launch_bounds__(256) void btgemm_k(const u16* __restrict__ A0,
                                                const u16* __restrict__ B0,
                                                CT* __restrict__ C,
                                                u16* __restrict__ Vt,
                                                int M, int N, int K) {
  __shared__ u16 As[128 * 64];
  __shared__ u16 Bs[128 * 64];
  int nnt = N >> 7;
  int bid = blockIdx.x;
  int nwg = gridDim.x;
  if ((nwg & 7) == 0) { int q = nwg >> 3; bid = (bid & 7) * q + (bid >> 3); }  // XCD swizzle
  int mt = bid / nnt, nt = bid - mt * nnt;
  int tid = threadIdx.x, wave = tid >> 6, lane = tid & 63;
  int l15 = lane & 15, l4 = lane >> 4;
  int wr = wave >> 1, wc = wave & 1;
  int sr = lane >> 3, sc = lane & 7;
  int gsl = (sc ^ sr) * 8;  // pre-swizzled source slot (elements)

  const u16* Ag = A0 + (size_t)(mt * 128 + wave * 32 + sr) * K + gsl;
  const u16* Bg = B0 + (size_t)(nt * 128 + wave * 32 + sr) * K + gsl;
  u16* Asw = As + wave * 32 * 64;
  u16* Bsw = Bs + wave * 32 * 64;

  f32x4 acc[4][4];
#pragma unroll
  for (int i = 0; i < 4; ++i)
#pragma unroll
    for (int j = 0; j < 4; ++j) acc[i][j] = f32x4{0.f, 0.f, 0.f, 0.f};

  for (int kt = 0; kt < K; kt += 64) {
#pragma unroll
    for (int i = 0; i < 4; ++i) {
      gload16(Ag + kt + i * 8 * K, Asw + i * 512);
      gload16(Bg + kt + i * 8 * K, Bsw + i * 512);
    }
    __syncthreads();
#pragma unroll
    for (int kk = 0; kk < 2; ++kk) {
      s16x8 af[4], bfr[4];
#pragma unroll
      for (int mf = 0; mf < 4; ++mf) {
        int row = wr * 64 + mf * 16 + l15;
        int sl = ((kk * 4 + l4) ^ (row & 7)) * 8;
        af[mf] = *(const s16x8*)(As + row * 64 + sl);
      }
#pragma unroll
      for (int nf = 0; nf < 4; ++nf) {
        int row = wc * 64 + nf * 16 + l15;
        int sl = ((kk * 4 + l4) ^ (row & 7)) * 8;
        bfr[nf] = *(const s16x8*)(Bs + row * 64 + sl);
      }
#pragma unroll
      for (int mf = 0; mf < 4; ++mf)
#pragma unroll
        for (int nf = 0; nf < 4; ++nf)
          acc[mf][nf] = __builtin_amdgcn_mfma_f32_16x16x32_bf16(af[mf], bfr[nf], acc[mf][nf], 0, 0, 0);
    }
    __syncthreads();
  }

  int crow = mt * 128 + wr * 64 + l4 * 4;
  int ccol = nt * 128 + wc * 64 + l15;
#pragma unroll
  for (int mf = 0; mf < 4; ++mf)
#pragma unroll
    for (int nf = 0; nf < 4; ++nf) {
      int col = ccol + nf * 16;
      int row0 = crow + mf * 16;
      if (VOUT && col >= 4096) {
        int h = (col - 4096) >> 7, dh = (col - 4096) & 127;
        int b = row0 >> 11, s0 = row0 & 2047;
        u16x4 w;
        w.x = f2bfh(acc[mf][nf][0]); w.y = f2bfh(acc[mf][nf][1]);
        w.z = f2bfh(acc[mf][nf][2]); w.w = f2bfh(acc[mf][nf][3]);
        *(u16x4*)(Vt + ((size_t)((b << 4) + h) * 128 + dh) * 2048 + s0) = w;
      } else {
#pragma unroll
        for (int r = 0; r < 4; ++r) {
          size_t idx = (size_t)(row0 + r) * N + col;
          float v = acc[mf][nf][r];
          if constexpr (OUTMODE == 0) C[idx] = v; else C[idx] = f2bfh(v);
        }
      }
    }
}

// ------------- MFMA flash attention v8: 8 waves x 16 q-rows (occupancy repartition) -------
// Same arithmetic as v7; per-wave work halved, VGPR <=128 -> 4 waves/SIMD (16 waves/CU).
__global__ __launch_bounds__(512, 4) void attn8_k(const u16* __restrict__ qkv,
                                                  const u16* __restrict__ Vt,
                                                  u16* __restrict__ outl) {
  __shared__ u16 Ks[64 * 128];     // [kv][d], XOR-swizzled 16B slots (16KB)
  __shared__ u16 Vs[128 * 64];     // [dh][kv], XOR-swizzled (16KB)
  __shared__ u16 Ps2[8 * 16 * 64]; // per-wave P[q][kv] (16KB)

  int bid = blockIdx.x;
  int xcd = bid & 7, slot = bid >> 3;  // bh->XCD locality
  int bh = xcd * 8 + (slot >> 4), qb = slot & 15;
  int b = bh >> 4, h = bh & 15;
  int tid = threadIdx.x, wave = tid >> 6, lane = tid & 63;
  int l15 = lane & 15, l4 = lane >> 4;
  int q0 = qb * 128 + wave * 16;  // 16 q-rows per wave
  const float ksc = 0.12751743f;  // log2(e)/sqrt(128)

  s16x8 qf[4];
#pragma unroll
  for (int kf = 0; kf < 4; ++kf)
    qf[kf] = *(const s16x8*)(qkv + (size_t)(b * 2048 + q0 + l15) * 6144 +
                             h * 128 + kf * 32 + l4 * 8);

  f32x4 po[8];
  float smrun = -1e30f, lrun = 0.f;  // smrun tracks m*ksc (log2 units)
#pragma unroll
  for (int n2 = 0; n2 < 8; ++n2) po[n2] = f32x4{0.f, 0.f, 0.f, 0.f};

  char* PsW = (char*)Ps2 + wave * 2048;  // 16 rows x 128B

  int krow_b = wave * 8;    // wave's K rows: +i*4 + (lane>>4), i in 0..1
  int vrow_b = wave * 16;   // wave's V rows: +i*8 + (lane>>3), i in 0..1
  int kj = lane & 15;
  int vj = lane & 7;

  s16x8 kr[2], vr[2];
#define GLOAD_TILE(kv0)                                                                  \
  _Pragma("unroll") for (int i = 0; i < 2; ++i) {                                        \
    int row = krow_b + i * 4 + (lane >> 4);                                              \
    kr[i] = *(const s16x8*)(qkv + (size_t)(b * 2048 + (kv0) + row) * 6144 + 2048 +       \
                            h * 128 + kj * 8);                                           \
    int row2 = vrow_b + i * 8 + (lane >> 3);                                             \
    vr[i] = *(const s16x8*)(Vt + (size_t)(bh * 128 + row2) * 2048 + (kv0) + vj * 8);     \
  }

  GLOAD_TILE(0)

  for (int t = 0; t < 32; ++t) {
    __syncthreads();
#pragma unroll
    for (int i = 0; i < 2; ++i) {
      int row = krow_b + i * 4 + (lane >> 4);
      *(s16x8*)(Ks + row * 128 + ((kj ^ (row & 7)) * 8)) = kr[i];
      int row2 = vrow_b + i * 8 + (lane >> 3);
      *(s16x8*)(Vs + row2 * 64 + ((vj ^ (row2 & 7)) * 8)) = vr[i];
    }
    __syncthreads();
    if (t < 31) GLOAD_TILE((t + 1) * 64)

    // ---- QK^T (swapped: A=K, B=Q) -> sa[nf]: kv=nf*16+l4*4+r, q=l15 ----
    f32x4 sa[4];
#pragma unroll
    for (int nf = 0; nf < 4; ++nf) sa[nf] = f32x4{0.f, 0.f, 0.f, 0.f};
    __builtin_amdgcn_s_setprio(1);
#pragma unroll
    for (int kf = 0; kf < 4; ++kf) {
      s16x8 kb[4];
#pragma unroll
      for (int nf = 0; nf < 4; ++nf) {
        int row = nf * 16 + l15;
        int sl = ((kf * 4 + l4) ^ (row & 7)) * 8;
        kb[nf] = *(const s16x8*)(Ks + row * 128 + sl);
      }
#pragma unroll
      for (int nf = 0; nf < 4; ++nf)
        sa[nf] = __builtin_amdgcn_mfma_f32_16x16x32_bf16(kb[nf], qf[kf], sa[nf], 0, 0, 0);
    }
    __builtin_amdgcn_s_setprio(0);

    // ---- in-register online softmax (lane owns q=l15; 16 kv values) ----
    {
      float m01 = fmaxf(fmaxf(sa[0][0], sa[0][1]), fmaxf(sa[0][2], sa[0][3]));
      float m23 = fmaxf(fmaxf(sa[1][0], sa[1][1]), fmaxf(sa[1][2], sa[1][3]));
      float m45 = fmaxf(fmaxf(sa[2][0], sa[2][1]), fmaxf(sa[2][2], sa[2][3]));
      float m67 = fmaxf(fmaxf(sa[3][0], sa[3][1]), fmaxf(sa[3][2], sa[3][3]));
      float pmax = fmaxf(fmaxf(m01, m23), fmaxf(m45, m67));
      pmax = fmaxf(pmax, __shfl_xor(pmax, 16, 64));
      pmax = fmaxf(pmax, __shfl_xor(pmax, 32, 64));
      float smax = pmax * ksc;
      if (!__all(smax - smrun <= 8.0f)) {  // T13 defer-max
        float mnew = fmaxf(smrun, smax);
        float fsc = exp2f(smrun - mnew);
        lrun *= fsc;
#pragma unroll
        for (int n2 = 0; n2 < 8; ++n2)
#pragma unroll
          for (int r = 0; r < 4; ++r) po[n2][r] *= fsc;
        smrun = mnew;
      }
      int row = l15;
      int swz = (row & 7) << 4;
      float ssum = 0.f;
#pragma unroll
      for (int nf = 0; nf < 4; ++nf) {
        float p0 = exp2f(fmaf(sa[nf][0], ksc, -smrun));
        float p1 = exp2f(fmaf(sa[nf][1], ksc, -smrun));
        float p2 = exp2f(fmaf(sa[nf][2], ksc, -smrun));
        float p3 = exp2f(fmaf(sa[nf][3], ksc, -smrun));
        ssum += (p0 + p1) + (p2 + p3);
        u16x4 w;
        w.x = f2bfh(p0); w.y = f2bfh(p1); w.z = f2bfh(p2); w.w = f2bfh(p3);
        *(u16x4*)(PsW + row * 128 + (((nf * 4 + l4) * 8) ^ swz)) = w;
      }
      ssum += __shfl_xor(ssum, 16, 64);
      ssum += __shfl_xor(ssum, 32, 64);
      lrun += ssum;
    }

    // ---- P fragments (B-operand: q=l15, kv slots k2*32+l4*8..+7) ----
    s16x8 pb[2];
    {
      int row = l15;
      int swz = (row & 7) << 4;
#pragma unroll
      for (int k2 = 0; k2 < 2; ++k2)
        pb[k2] = *(const s16x8*)(PsW + row * 128 + ((k2 * 64 + l4 * 16) ^ swz));
    }

    // ---- PV (A=V^T, B=P): po[n2]: dh=n2*16+l4*4+r, q=l15 ----
    __builtin_amdgcn_s_setprio(1);
#pragma unroll
    for (int n2 = 0; n2 < 8; ++n2) {
#pragma unroll
      for (int k2 = 0; k2 < 2; ++k2) {
        int row = n2 * 16 + l15;
        int sl = ((k2 * 4 + l4) ^ (row & 7)) * 8;
        s16x8 vb = *(const s16x8*)(Vs + row * 64 + sl);
        po[n2] = __builtin_amdgcn_mfma_f32_16x16x32_bf16(vb, pb[k2], po[n2], 0, 0, 0);
      }
    }
    __builtin_amdgcn_s_setprio(0);
  }
#undef GLOAD_TILE

  // epilogue: normalize + vectorized store (token = q0+l15, dh = n2*16+l4*4..+3)
  {
    float inv = 1.0f / lrun;
#pragma unroll
    for (int n2 = 0; n2 < 8; ++n2) {
      u16x4 w;
      w.x = f2bfh(po[n2][0] * inv);
      w.y = f2bfh(po[n2][1] * inv);
      w.z = f2bfh(po[n2][2] * inv);
      w.w = f2bfh(po[n2][3] * inv);
      *(u16x4*)(outl + (size_t)(b * 2048 + q0 + l15) * 2048 + h * 128 + n2 * 16 + l4 * 4) = w;
    }
  }
}

extern "C" void kernel_launch(void* const* d_in, const int* in_sizes, int n_in,
                              void* d_out, int out_size, void* d_ws, size_t ws_size,
                              hipStream_t stream) {
  (void)in_sizes; (void)n_in;
  const float* hs  = (const float*)d_in[0];
  const float* Wq  = (const float*)d_in[1];
  const float* Wkd = (const float*)d_in[2];
  const float* Wvd = (const float*)d_in[3];
  const float* Wku = (const float*)d_in[4];
  const float* Wo  = (const float*)d_in[5];
  float* out = (float*)d_out;
  char* ws = (char*)d_ws;

  // ws sentinel: need 192 MiB
  if (ws_size < 201326592ull) {
    fill_k<<<4096, 256, 0, stream>>>(out, out_size, 1e9f);
    return;
  }

  // workspace layout (192 MiB), time-multiplexed:
  //  [0,        25.17M) W3   (cvtall -> qkv GEMM)
  //  [25.17M,   33.55M) WcH  (Wc GEMM -> final GEMM)
  //  [33.55M,   67.11M) hsB  (cvtall -> qkv GEMM); then outl (attn -> final GEMM)
  //  [67.11M,  167.77M) qkv  (q|k cols only; v cols unwritten)
  //  [167.77M, 201.33M) WoB|WkuT (cvtall/cvtT -> Wc GEMM); then Vt (qkv GEMM -> attn)
  u16* W3   = (u16*)(ws);
  u16* WcH  = (u16*)(ws + 25165824);
  u16* hsB  = (u16*)(ws + 33554432);
  u16* outl = (u16*)(ws + 33554432);
  u16* qkv  = (u16*)(ws + 67108864);
  u16* WoB  = (u16*)(ws + 167772160);
  u16* WkuT = (u16*)(ws + 176160768);
  u16* Vt   = (u16*)(ws + 167772160);

  cvtall_k<<<32768, 256, 0, stream>>>(hs, Wq, Wkd, Wvd, Wo, hsB, W3, WoB);
  cvtT_k<<<dim3(64, 64), dim3(32, 8), 0, stream>>>(Wku, WkuT);

  // Wc = Wo @ Wk_up  (must precede qkv GEMM: Vt overwrites WoB/WkuT region)
  btgemm_k<u16, 1, false><<<256, 256, 0, stream>>>(WoB, WkuT, WcH, nullptr, 2048, 2048, 2048);

  // qkv = hsB @ [Wq|Wk_down|Wv_down]^T ; v columns routed transposed into Vt
  btgemm_k<u16, 1, true><<<3072, 256, 0, stream>>>(hsB, W3, qkv, Vt, 8192, 6144, 2048);

  attn8_k<<<1024, 512, 0, stream>>>(qkv, Vt, outl);

  // out = out_lat @ Wc^T  (fp32 out)
  btgemm_k<float, 0, false><<<1024, 256, 0, stream>>>(outl, WcH, out, nullptr, 8192, 2048, 2048);
}

// Round 12
// 579.287 us; speedup vs baseline: 1.9737x; 1.0218x over previous
//
#include <hip/hip_runtime.h>
#include <hip/hip_bf16.h>
#include <stdint.h>

typedef unsigned short u16;
typedef __attribute__((ext_vector_type(4))) float f32x4;
typedef __attribute__((ext_vector_type(8))) short s16x8;
typedef __attribute__((ext_vector_type(4))) u16 u16x4;

__device__ __forceinline__ u16 f2bf(float x) {
  union { float f; uint32_t u; } v; v.f = x;
  uint32_t r = v.u + 0x7FFFu + ((v.u >> 16) & 1u);
  return (u16)(r >> 16);
}
// compiler-recognized scalar cast (emits native cvt; pairs into cvt_pk) [m240]
__device__ __forceinline__ u16 f2bfh(float x) {
  __hip_bfloat16 h = __float2bfloat16(x);
  u16 r; __builtin_memcpy(&r, &h, 2); return r;
}

__device__ __forceinline__ void gload16(const void* g, const void* l) {
  __builtin_amdgcn_global_load_lds((const __attribute__((address_space(1))) void*)g,
                                   (__attribute__((address_space(3))) void*)l,
                                   16, 0, 0);
}

__global__ void fill_k(float* out, int n, float v) {
  for (int i = blockIdx.x * blockDim.x + threadIdx.x; i < n; i += gridDim.x * blockDim.x)
    out[i] = v;
}

// ------------- fused fp32 -> bf16 convert for hs, Wq, Wkd, Wvd, Wo (one launch) -------------
__global__ void cvtall_k(const float* __restrict__ hs, const float* __restrict__ Wq,
                         const float* __restrict__ Wkd, const float* __restrict__ Wvd,
                         const float* __restrict__ Wo,
                         u16* __restrict__ hsB, u16* __restrict__ W3, u16* __restrict__ WoB) {
  int i = blockIdx.x * blockDim.x + threadIdx.x;  // f32x4 units, total 8388608
  const float* src; u16* dst; int off;
  if (i < 4194304)      { src = hs;  dst = hsB;          off = i; }
  else if (i < 5242880) { src = Wq;  dst = W3;           off = i - 4194304; }
  else if (i < 6291456) { src = Wkd; dst = W3 + 4194304; off = i - 5242880; }
  else if (i < 7340032) { src = Wvd; dst = W3 + 8388608; off = i - 6291456; }
  else                  { src = Wo;  dst = WoB;          off = i - 7340032; }
  f32x4 v = ((const f32x4*)src)[off];
  u16x4 o;
  o.x = f2bf(v.x); o.y = f2bf(v.y); o.z = f2bf(v.z); o.w = f2bf(v.w);
  ((u16x4*)dst)[off] = o;
}

// ------------- fp32 [2048][2048] -> bf16 transposed -------------
__global__ void cvtT_k(const float* __restrict__ in, u16* __restrict__ out) {
  __shared__ float t[32][33];
  int tx = threadIdx.x, ty = threadIdx.y;
  int c = blockIdx.x * 32 + tx;
#pragma unroll
  for (int j = 0; j < 4; ++j) {
    int r = blockIdx.y * 32 + ty + j * 8;
    t[ty + j * 8][tx] = in[(size_t)r * 2048 + c];
  }
  __syncthreads();
  int c2 = blockIdx.y * 32 + tx;
#pragma unroll
  for (int j = 0; j < 4; ++j) {
    int r2 = blockIdx.x * 32 + ty + j * 8;
    out[(size_t)r2 * 2048 + c2] = f2bf(t[tx][ty + j * 8]);
  }
}

// ------------- merged GEMM: blocks 0..3071 = qkv (M8192 N6144 K2048, q|k->qk, v->Vt),
//               blocks 3072..3327 = Wc (Wo @ Wk_up, 2048^3) — fills qkv's tail slack -----
__global__ __launch_bounds__(256) void gemm_qkvwc_k(const u16* __restrict__ hsB,
                                                    const u16* __restrict__ W3,
                                                    u16* __restrict__ qk,
                                                    u16* __restrict__ Vt,
                                                    const u16* __restrict__ WoB,
                                                    const u16* __restrict__ WkuT,
                                                    u16* __restrict__ WcH) {
  __shared__ u16 As[128 * 64];
  __shared__ u16 Bs[128 * 64];
  int bid = blockIdx.x;
  int bid2 = (bid & 7) * 416 + (bid >> 3);  // bijective XCD swizzle (nwg=3328)
  const u16 *A0, *B0;
  int mt, nt; bool isW;
  if (bid2 < 3072) { isW = false; mt = bid2 / 48; nt = bid2 - mt * 48; A0 = hsB; B0 = W3; }
  else { int ix = bid2 - 3072; isW = true; mt = ix >> 4; nt = ix & 15; A0 = WoB; B0 = WkuT; }
  const int K = 2048;
  int tid = threadIdx.x, wave = tid >> 6, lane = tid & 63;
  int l15 = lane & 15, l4 = lane >> 4;
  int wr = wave >> 1, wc = wave & 1;
  int sr = lane >> 3, sc = lane & 7;
  int gsl = (sc ^ sr) * 8;

  const u16* Ag = A0 + (size_t)(mt * 128 + wave * 32 + sr) * K + gsl;
  const u16* Bg = B0 + (size_t)(nt * 128 + wave * 32 + sr) * K + gsl;
  u16* Asw = As + wave * 32 * 64;
  u16* Bsw = Bs + wave * 32 * 64;

  f32x4 acc[4][4];
#pragma unroll
  for (int i = 0; i < 4; ++i)
#pragma unroll
    for (int j = 0; j < 4; ++j) acc[i][j] = f32x4{0.f, 0.f, 0.f, 0.f};

  for (int kt = 0; kt < K; kt += 64) {
#pragma unroll
    for (int i = 0; i < 4; ++i) {
      gload16(Ag + kt + i * 8 * K, Asw + i * 512);
      gload16(Bg + kt + i * 8 * K, Bsw + i * 512);
    }
    __syncthreads();
#pragma unroll
    for (int kk = 0; kk < 2; ++kk) {
      s16x8 af[4], bfr[4];
#pragma unroll
      for (int mf = 0; mf < 4; ++mf) {
        int row = wr * 64 + mf * 16 + l15;
        int sl = ((kk * 4 + l4) ^ (row & 7)) * 8;
        af[mf] = *(const s16x8*)(As + row * 64 + sl);
      }
#pragma unroll
      for (int nf = 0; nf < 4; ++nf) {
        int row = wc * 64 + nf * 16 + l15;
        int sl = ((kk * 4 + l4) ^ (row & 7)) * 8;
        bfr[nf] = *(const s16x8*)(Bs + row * 64 + sl);
      }
#pragma unroll
      for (int mf = 0; mf < 4; ++mf)
#pragma unroll
        for (int nf = 0; nf < 4; ++nf)
          acc[mf][nf] = __builtin_amdgcn_mfma_f32_16x16x32_bf16(af[mf], bfr[nf], acc[mf][nf], 0, 0, 0);
    }
    __syncthreads();
  }

  int crow = mt * 128 + wr * 64 + l4 * 4;
  int ccol = nt * 128 + wc * 64 + l15;
#pragma unroll
  for (int mf = 0; mf < 4; ++mf)
#pragma unroll
    for (int nf = 0; nf < 4; ++nf) {
      int col = ccol + nf * 16;
      int row0 = crow + mf * 16;
      if (isW) {
#pragma unroll
        for (int r = 0; r < 4; ++r)
          WcH[(size_t)(row0 + r) * 2048 + col] = f2bfh(acc[mf][nf][r]);
      } else if (col >= 4096) {
        // transposed V store: Vt[(b*16+h)*128 + dh][s0..s0+3]
        int h = (col - 4096) >> 7, dh = (col - 4096) & 127;
        int b = row0 >> 11, s0 = row0 & 2047;
        u16x4 w;
        w.x = f2bfh(acc[mf][nf][0]); w.y = f2bfh(acc[mf][nf][1]);
        w.z = f2bfh(acc[mf][nf][2]); w.w = f2bfh(acc[mf][nf][3]);
        *(u16x4*)(Vt + ((size_t)((b << 4) + h) * 128 + dh) * 2048 + s0) = w;
      } else {
#pragma unroll
        for (int r = 0; r < 4; ++r)
          qk[(size_t)(row0 + r) * 4096 + col] = f2bfh(acc[mf][nf][r]);
      }
    }
}

// ------------- bf16 GEMM (final): C[M][N] = A[M][K] * B[N][K]^T, fp32 out -------------
__global__ __launch_bounds__(256) void btgemm_k(const u16* __restrict__ A0,
                                                const u16* __restrict__ B0,
                                                float* __restrict__ C,
                                                int M, int N, int K) {
  __shared__ u16 As[128 * 64];
  __shared__ u16 Bs[128 * 64];
  int nnt = N >> 7;
  int bid = blockIdx.x;
  int nwg = gridDim.x;
  if ((nwg & 7) == 0) { int q = nwg >> 3; bid = (bid & 7) * q + (bid >> 3); }
  int mt = bid / nnt, nt = bid - mt * nnt;
  int tid = threadIdx.x, wave = tid >> 6, lane = tid & 63;
  int l15 = lane & 15, l4 = lane >> 4;
  int wr = wave >> 1, wc = wave & 1;
  int sr = lane >> 3, sc = lane & 7;
  int gsl = (sc ^ sr) * 8;

  const u16* Ag = A0 + (size_t)(mt * 128 + wave * 32 + sr) * K + gsl;
  const u16* Bg = B0 + (size_t)(nt * 128 + wave * 32 + sr) * K + gsl;
  u16* Asw = As + wave * 32 * 64;
  u16* Bsw = Bs + wave * 32 * 64;

  f32x4 acc[4][4];
#pragma unroll
  for (int i = 0; i < 4; ++i)
#pragma unroll
    for (int j = 0; j < 4; ++j) acc[i][j] = f32x4{0.f, 0.f, 0.f, 0.f};

  for (int kt = 0; kt < K; kt += 64) {
#pragma unroll
    for (int i = 0; i < 4; ++i) {
      gload16(Ag + kt + i * 8 * K, Asw + i * 512);
      gload16(Bg + kt + i * 8 * K, Bsw + i * 512);
    }
    __syncthreads();
#pragma unroll
    for (int kk = 0; kk < 2; ++kk) {
      s16x8 af[4], bfr[4];
#pragma unroll
      for (int mf = 0; mf < 4; ++mf) {
        int row = wr * 64 + mf * 16 + l15;
        int sl = ((kk * 4 + l4) ^ (row & 7)) * 8;
        af[mf] = *(const s16x8*)(As + row * 64 + sl);
      }
#pragma unroll
      for (int nf = 0; nf < 4; ++nf) {
        int row = wc * 64 + nf * 16 + l15;
        int sl = ((kk * 4 + l4) ^ (row & 7)) * 8;
        bfr[nf] = *(const s16x8*)(Bs + row * 64 + sl);
      }
#pragma unroll
      for (int mf = 0; mf < 4; ++mf)
#pragma unroll
        for (int nf = 0; nf < 4; ++nf)
          acc[mf][nf] = __builtin_amdgcn_mfma_f32_16x16x32_bf16(af[mf], bfr[nf], acc[mf][nf], 0, 0, 0);
    }
    __syncthreads();
  }

  int crow = mt * 128 + wr * 64 + l4 * 4;
  int ccol = nt * 128 + wc * 64 + l15;
#pragma unroll
  for (int mf = 0; mf < 4; ++mf)
#pragma unroll
    for (int nf = 0; nf < 4; ++nf)
#pragma unroll
      for (int r = 0; r < 4; ++r)
        C[(size_t)(crow + mf * 16 + r) * N + (ccol + nf * 16)] = acc[mf][nf][r];
}

// ------------- MFMA flash attention v9: attn8 + K/V double-buffer (1 barrier/tile) -------
// qk: [8192][4096] bf16 (q|k). Vt: [64][128][2048] bf16. outl: [8192][2048] bf16.
__global__ __launch_bounds__(512, 4) void attn9_k(const u16* __restrict__ qk,
                                                  const u16* __restrict__ Vt,
                                                  u16* __restrict__ outl) {
  __shared__ u16 Ks[2][64 * 128];  // dbuf [kv][d], XOR-swizzled (32KB)
  __shared__ u16 Vs[2][128 * 64];  // dbuf [dh][kv], XOR-swizzled (32KB)
  __shared__ u16 Ps2[8 * 16 * 64]; // per-wave P[q][kv] (16KB)

  int bid = blockIdx.x;
  int xcd = bid & 7, slot = bid >> 3;  // bh->XCD locality
  int bh = xcd * 8 + (slot >> 4), qb = slot & 15;
  int b = bh >> 4, h = bh & 15;
  int tid = threadIdx.x, wave = tid >> 6, lane = tid & 63;
  int l15 = lane & 15, l4 = lane >> 4;
  int q0 = qb * 128 + wave * 16;  // 16 q-rows per wave
  const float ksc = 0.12751743f;  // log2(e)/sqrt(128)

  s16x8 qf[4];
#pragma unroll
  for (int kf = 0; kf < 4; ++kf)
    qf[kf] = *(const s16x8*)(qk + (size_t)(b * 2048 + q0 + l15) * 4096 +
                             h * 128 + kf * 32 + l4 * 8);

  f32x4 po[8];
  float smrun = -1e30f, lrun = 0.f;
#pragma unroll
  for (int n2 = 0; n2 < 8; ++n2) po[n2] = f32x4{0.f, 0.f, 0.f, 0.f};

  char* PsW = (char*)Ps2 + wave * 2048;

  int krow_b = wave * 8;
  int vrow_b = wave * 16;
  int kj = lane & 15;
  int vj = lane & 7;

  s16x8 kr[2], vr[2];
#define GLOAD_TILE(kv0)                                                                  \
  _Pragma("unroll") for (int i = 0; i < 2; ++i) {                                        \
    int row = krow_b + i * 4 + (lane >> 4);                                              \
    kr[i] = *(const s16x8*)(qk + (size_t)(b * 2048 + (kv0) + row) * 4096 + 2048 +        \
                            h * 128 + kj * 8);                                           \
    int row2 = vrow_b + i * 8 + (lane >> 3);                                             \
    vr[i] = *(const s16x8*)(Vt + (size_t)(bh * 128 + row2) * 2048 + (kv0) + vj * 8);     \
  }

  GLOAD_TILE(0)

  for (int t = 0; t < 32; ++t) {
    int cur = t & 1;
    u16* Ksc = Ks[cur];
    u16* Vsc = Vs[cur];
    // write staged regs into current buffer, then single barrier
#pragma unroll
    for (int i = 0; i < 2; ++i) {
      int row = krow_b + i * 4 + (lane >> 4);
      *(s16x8*)(Ksc + row * 128 + ((kj ^ (row & 7)) * 8)) = kr[i];
      int row2 = vrow_b + i * 8 + (lane >> 3);
      *(s16x8*)(Vsc + row2 * 64 + ((vj ^ (row2 & 7)) * 8)) = vr[i];
    }
    __syncthreads();
    if (t < 31) GLOAD_TILE((t + 1) * 64)  // latency hides under full tile compute

    // ---- QK^T (swapped: A=K, B=Q) ----
    f32x4 sa[4];
#pragma unroll
    for (int nf = 0; nf < 4; ++nf) sa[nf] = f32x4{0.f, 0.f, 0.f, 0.f};
    __builtin_amdgcn_s_setprio(1);
#pragma unroll
    for (int kf = 0; kf < 4; ++kf) {
      s16x8 kb[4];
#pragma unroll
      for (int nf = 0; nf < 4; ++nf) {
        int row = nf * 16 + l15;
        int sl = ((kf * 4 + l4) ^ (row & 7)) * 8;
        kb[nf] = *(const s16x8*)(Ksc + row * 128 + sl);
      }
#pragma unroll
      for (int nf = 0; nf < 4; ++nf)
        sa[nf] = __builtin_amdgcn_mfma_f32_16x16x32_bf16(kb[nf], qf[kf], sa[nf], 0, 0, 0);
    }
    __builtin_amdgcn_s_setprio(0);

    // ---- in-register online softmax ----
    {
      float m01 = fmaxf(fmaxf(sa[0][0], sa[0][1]), fmaxf(sa[0][2], sa[0][3]));
      float m23 = fmaxf(fmaxf(sa[1][0], sa[1][1]), fmaxf(sa[1][2], sa[1][3]));
      float m45 = fmaxf(fmaxf(sa[2][0], sa[2][1]), fmaxf(sa[2][2], sa[2][3]));
      float m67 = fmaxf(fmaxf(sa[3][0], sa[3][1]), fmaxf(sa[3][2], sa[3][3]));
      float pmax = fmaxf(fmaxf(m01, m23), fmaxf(m45, m67));
      pmax = fmaxf(pmax, __shfl_xor(pmax, 16, 64));
      pmax = fmaxf(pmax, __shfl_xor(pmax, 32, 64));
      float smax = pmax * ksc;
      if (!__all(smax - smrun <= 8.0f)) {  // T13 defer-max
        float mnew = fmaxf(smrun, smax);
        float fsc = exp2f(smrun - mnew);
        lrun *= fsc;
#pragma unroll
        for (int n2 = 0; n2 < 8; ++n2)
#pragma unroll
          for (int r = 0; r < 4; ++r) po[n2][r] *= fsc;
        smrun = mnew;
      }
      int row = l15;
      int swz = (row & 7) << 4;
      float ssum = 0.f;
#pragma unroll
      for (int nf = 0; nf < 4; ++nf) {
        float p0 = exp2f(fmaf(sa[nf][0], ksc, -smrun));
        float p1 = exp2f(fmaf(sa[nf][1], ksc, -smrun));
        float p2 = exp2f(fmaf(sa[nf][2], ksc, -smrun));
        float p3 = exp2f(fmaf(sa[nf][3], ksc, -smrun));
        ssum += (p0 + p1) + (p2 + p3);
        u16x4 w;
        w.x = f2bfh(p0); w.y = f2bfh(p1); w.z = f2bfh(p2); w.w = f2bfh(p3);
        *(u16x4*)(PsW + row * 128 + (((nf * 4 + l4) * 8) ^ swz)) = w;
      }
      ssum += __shfl_xor(ssum, 16, 64);
      ssum += __shfl_xor(ssum, 32, 64);
      lrun += ssum;
    }

    // ---- P fragments ----
    s16x8 pb[2];
    {
      int row = l15;
      int swz = (row & 7) << 4;
#pragma unroll
      for (int k2 = 0; k2 < 2; ++k2)
        pb[k2] = *(const s16x8*)(PsW + row * 128 + ((k2 * 64 + l4 * 16) ^ swz));
    }

    // ---- PV (A=V^T, B=P) ----
    __builtin_amdgcn_s_setprio(1);
#pragma unroll
    for (int n2 = 0; n2 < 8; ++n2) {
#pragma unroll
      for (int k2 = 0; k2 < 2; ++k2) {
        int row = n2 * 16 + l15;
        int sl = ((k2 * 4 + l4) ^ (row & 7)) * 8;
        s16x8 vb = *(const s16x8*)(Vsc + row * 64 + sl);
        po[n2] = __builtin_amdgcn_mfma_f32_16x16x32_bf16(vb, pb[k2], po[n2], 0, 0, 0);
      }
    }
    __builtin_amdgcn_s_setprio(0);
  }
#undef GLOAD_TILE

  // epilogue
  {
    float inv = 1.0f / lrun;
#pragma unroll
    for (int n2 = 0; n2 < 8; ++n2) {
      u16x4 w;
      w.x = f2bfh(po[n2][0] * inv);
      w.y = f2bfh(po[n2][1] * inv);
      w.z = f2bfh(po[n2][2] * inv);
      w.w = f2bfh(po[n2][3] * inv);
      *(u16x4*)(outl + (size_t)(b * 2048 + q0 + l15) * 2048 + h * 128 + n2 * 16 + l4 * 4) = w;
    }
  }
}

extern "C" void kernel_launch(void* const* d_in, const int* in_sizes, int n_in,
                              void* d_out, int out_size, void* d_ws, size_t ws_size,
                              hipStream_t stream) {
  (void)in_sizes; (void)n_in;
  const float* hs  = (const float*)d_in[0];
  const float* Wq  = (const float*)d_in[1];
  const float* Wkd = (const float*)d_in[2];
  const float* Wvd = (const float*)d_in[3];
  const float* Wku = (const float*)d_in[4];
  const float* Wo  = (const float*)d_in[5];
  float* out = (float*)d_out;
  char* ws = (char*)d_ws;

  // ws sentinel: need 192 MiB
  if (ws_size < 201326592ull) {
    fill_k<<<4096, 256, 0, stream>>>(out, out_size, 1e9f);
    return;
  }

  // workspace layout (192 MiB):
  //  [0,        25.17M) W3   (cvtall -> merged GEMM)
  //  [25.17M,   33.55M) WcH  (merged GEMM -> final GEMM)
  //  [33.55M,   67.11M) hsB  (cvtall -> merged GEMM); then outl (attn -> final GEMM)
  //  [67.11M,  134.22M) qk   [8192][4096] bf16 (q|k)
  //  [134.22M, 142.61M) WoB ; [142.61M, 150.99M) WkuT   (no aliasing with Vt now)
  //  [167.77M, 201.33M) Vt
  u16* W3   = (u16*)(ws);
  u16* WcH  = (u16*)(ws + 25165824);
  u16* hsB  = (u16*)(ws + 33554432);
  u16* outl = (u16*)(ws + 33554432);
  u16* qk   = (u16*)(ws + 67108864);
  u16* WoB  = (u16*)(ws + 134217728);
  u16* WkuT = (u16*)(ws + 142606336);
  u16* Vt   = (u16*)(ws + 167772160);

  cvtall_k<<<32768, 256, 0, stream>>>(hs, Wq, Wkd, Wvd, Wo, hsB, W3, WoB);
  cvtT_k<<<dim3(64, 64), dim3(32, 8), 0, stream>>>(Wku, WkuT);

  // merged: qkv projections (+V transpose) and Wc = Wo @ Wk_up in one launch
  gemm_qkvwc_k<<<3328, 256, 0, stream>>>(hsB, W3, qk, Vt, WoB, WkuT, WcH);

  attn9_k<<<1024, 512, 0, stream>>>(qk, Vt, outl);

  // out = out_lat @ Wc^T  (fp32 out)
  btgemm_k<<<1024, 256, 0, stream>>>(outl, WcH, out, 8192, 2048, 2048);
}

// Round 13
// 538.648 us; speedup vs baseline: 2.1226x; 1.0754x over previous
//
#include <hip/hip_runtime.h>
#include <hip/hip_bf16.h>
#include <stdint.h>

typedef unsigned short u16;
typedef __attribute__((ext_vector_type(4))) float f32x4;
typedef __attribute__((ext_vector_type(8))) short s16x8;
typedef __attribute__((ext_vector_type(4))) u16 u16x4;

__device__ __forceinline__ u16 f2bf(float x) {
  union { float f; uint32_t u; } v; v.f = x;
  uint32_t r = v.u + 0x7FFFu + ((v.u >> 16) & 1u);
  return (u16)(r >> 16);
}
__device__ __forceinline__ u16 f2bfh(float x) {
  __hip_bfloat16 h = __float2bfloat16(x);
  u16 r; __builtin_memcpy(&r, &h, 2); return r;
}

__device__ __forceinline__ void gload16(const void* g, const void* l) {
  __builtin_amdgcn_global_load_lds((const __attribute__((address_space(1))) void*)g,
                                   (__attribute__((address_space(3))) void*)l,
                                   16, 0, 0);
}

#define BAR() asm volatile("s_barrier" ::: "memory")
#define VMCNT8() asm volatile("s_waitcnt vmcnt(8)" ::: "memory")
#define VMCNT0() asm volatile("s_waitcnt vmcnt(0)" ::: "memory")

__global__ void fill_k(float* out, int n, float v) {
  for (int i = blockIdx.x * blockDim.x + threadIdx.x; i < n; i += gridDim.x * blockDim.x)
    out[i] = v;
}

// ------------- fused fp32 -> bf16 convert for hs, Wq, Wkd, Wvd, Wo (one launch) -------------
__global__ void cvtall_k(const float* __restrict__ hs, const float* __restrict__ Wq,
                         const float* __restrict__ Wkd, const float* __restrict__ Wvd,
                         const float* __restrict__ Wo,
                         u16* __restrict__ hsB, u16* __restrict__ W3, u16* __restrict__ WoB) {
  int i = blockIdx.x * blockDim.x + threadIdx.x;  // f32x4 units, total 8388608
  const float* src; u16* dst; int off;
  if (i < 4194304)      { src = hs;  dst = hsB;          off = i; }
  else if (i < 5242880) { src = Wq;  dst = W3;           off = i - 4194304; }
  else if (i < 6291456) { src = Wkd; dst = W3 + 4194304; off = i - 5242880; }
  else if (i < 7340032) { src = Wvd; dst = W3 + 8388608; off = i - 6291456; }
  else                  { src = Wo;  dst = WoB;          off = i - 7340032; }
  f32x4 v = ((const f32x4*)src)[off];
  u16x4 o;
  o.x = f2bf(v.x); o.y = f2bf(v.y); o.z = f2bf(v.z); o.w = f2bf(v.w);
  ((u16x4*)dst)[off] = o;
}

// ------------- fp32 [2048][2048] -> bf16 transposed -------------
__global__ void cvtT_k(const float* __restrict__ in, u16* __restrict__ out) {
  __shared__ float t[32][33];
  int tx = threadIdx.x, ty = threadIdx.y;
  int c = blockIdx.x * 32 + tx;
#pragma unroll
  for (int j = 0; j < 4; ++j) {
    int r = blockIdx.y * 32 + ty + j * 8;
    t[ty + j * 8][tx] = in[(size_t)r * 2048 + c];
  }
  __syncthreads();
  int c2 = blockIdx.y * 32 + tx;
#pragma unroll
  for (int j = 0; j < 4; ++j) {
    int r2 = blockIdx.x * 32 + ty + j * 8;
    out[(size_t)r2 * 2048 + c2] = f2bf(t[tx][ty + j * 8]);
  }
}

// ------------- bf16 GEMM 128^2 (m97 structure): C[M][N] = A[M][K] * B[N][K]^T -------------
// OUTMODE: 0 = fp32, 1 = bf16
template <typename CT, int OUTMODE>
__global__ __launch_bounds__(256) void btgemm_k(const u16* __restrict__ A0,
                                                const u16* __restrict__ B0,
                                                CT* __restrict__ C,
                                                int M, int N, int K) {
  __shared__ u16 As[128 * 64];
  __shared__ u16 Bs[128 * 64];
  int nnt = N >> 7;
  int bid = blockIdx.x;
  int nwg = gridDim.x;
  if ((nwg & 7) == 0) { int q = nwg >> 3; bid = (bid & 7) * q + (bid >> 3); }
  int mt = bid / nnt, nt = bid - mt * nnt;
  int tid = threadIdx.x, wave = tid >> 6, lane = tid & 63;
  int l15 = lane & 15, l4 = lane >> 4;
  int wr = wave >> 1, wc = wave & 1;
  int sr = lane >> 3, sc = lane & 7;
  int gsl = (sc ^ sr) * 8;

  const u16* Ag = A0 + (size_t)(mt * 128 + wave * 32 + sr) * K + gsl;
  const u16* Bg = B0 + (size_t)(nt * 128 + wave * 32 + sr) * K + gsl;
  u16* Asw = As + wave * 32 * 64;
  u16* Bsw = Bs + wave * 32 * 64;

  f32x4 acc[4][4];
#pragma unroll
  for (int i = 0; i < 4; ++i)
#pragma unroll
    for (int j = 0; j < 4; ++j) acc[i][j] = f32x4{0.f, 0.f, 0.f, 0.f};

  for (int kt = 0; kt < K; kt += 64) {
#pragma unroll
    for (int i = 0; i < 4; ++i) {
      gload16(Ag + kt + i * 8 * K, Asw + i * 512);
      gload16(Bg + kt + i * 8 * K, Bsw + i * 512);
    }
    __syncthreads();
#pragma unroll
    for (int kk = 0; kk < 2; ++kk) {
      s16x8 af[4], bfr[4];
#pragma unroll
      for (int mf = 0; mf < 4; ++mf) {
        int row = wr * 64 + mf * 16 + l15;
        int sl = ((kk * 4 + l4) ^ (row & 7)) * 8;
        af[mf] = *(const s16x8*)(As + row * 64 + sl);
      }
#pragma unroll
      for (int nf = 0; nf < 4; ++nf) {
        int row = wc * 64 + nf * 16 + l15;
        int sl = ((kk * 4 + l4) ^ (row & 7)) * 8;
        bfr[nf] = *(const s16x8*)(Bs + row * 64 + sl);
      }
#pragma unroll
      for (int mf = 0; mf < 4; ++mf)
#pragma unroll
        for (int nf = 0; nf < 4; ++nf)
          acc[mf][nf] = __builtin_amdgcn_mfma_f32_16x16x32_bf16(af[mf], bfr[nf], acc[mf][nf], 0, 0, 0);
    }
    __syncthreads();
  }

  int crow = mt * 128 + wr * 64 + l4 * 4;
  int ccol = nt * 128 + wc * 64 + l15;
#pragma unroll
  for (int mf = 0; mf < 4; ++mf)
#pragma unroll
    for (int nf = 0; nf < 4; ++nf)
#pragma unroll
      for (int r = 0; r < 4; ++r) {
        size_t idx = (size_t)(crow + mf * 16 + r) * N + (ccol + nf * 16);
        float v = acc[mf][nf][r];
        if constexpr (OUTMODE == 0) C[idx] = v; else C[idx] = f2bfh(v);
      }
}

// ------------- 256^2 pipelined GEMM (T2+T3+T4+T5): qkv projections, v -> Vt transposed ----
// M=8192, N=6144, K=2048. 512 thr / 8 waves (2x4). BK=32, 4 LDS tile-slots (128 KB),
// stage tile t+3 during tile t, vmcnt(8) per tile (never 0), raw s_barrier per phase.
__global__ __launch_bounds__(512, 2) void gemm256qkv_k(const u16* __restrict__ A0,
                                                       const u16* __restrict__ B0,
                                                       u16* __restrict__ qk,
                                                       u16* __restrict__ Vt) {
  __shared__ u16 lds4[4][2][8192];  // [slot][A/B][256 rows x 32 cols], 128 KB

  const int K = 2048;
  int bid = blockIdx.x;
  int bid2 = (bid & 7) * 96 + (bid >> 3);  // bijective XCD swizzle (nwg=768)
  int mt = bid2 / 24, nt = bid2 - mt * 24;
  int tid = threadIdx.x, wave = tid >> 6, lane = tid & 63;
  int l15 = lane & 15, l4 = lane >> 4;
  int wr = wave >> 2, wc = wave & 3;

  // stage-side per-lane constants: chunk row = tid>>2 (128 rows), slot = tid&3
  int rowin = tid >> 2;
  int gsl = (tid & 3) ^ (rowin & 3) ^ ((rowin >> 2) & 3);
  const u16* Agst = A0 + (size_t)(mt * 256 + rowin) * K + gsl * 8;
  const u16* Bgst = B0 + (size_t)(nt * 256 + rowin) * K + gsl * 8;
  const size_t HSTRIDE = (size_t)128 * K;

  // read-side: logical slot l4 stored at sl = l4 ^ f(row), f = (row&3)^((row>>2)&3)
  int sl = l4 ^ (l15 & 3) ^ ((l15 >> 2) & 3);
  int aoff = wr * 4096 + l15 * 32 + sl * 8;  // + mf*512
  int boff = wc * 2048 + l15 * 32 + sl * 8;  // + nf*512

  f32x4 acc[8][4];
#pragma unroll
  for (int i = 0; i < 8; ++i)
#pragma unroll
    for (int j = 0; j < 4; ++j) acc[i][j] = f32x4{0.f, 0.f, 0.f, 0.f};

  // prologue: stage tiles 0,1,2 (4 chunks each), then ensure tile 0 landed
#pragma unroll
  for (int p = 0; p < 3; ++p) {
    gload16(Agst + p * 32, &lds4[p][0][wave * 512]);
    gload16(Agst + HSTRIDE + p * 32, &lds4[p][0][4096 + wave * 512]);
    gload16(Bgst + p * 32, &lds4[p][1][wave * 512]);
    gload16(Bgst + HSTRIDE + p * 32, &lds4[p][1][4096 + wave * 512]);
  }
  VMCNT8();
  BAR();

  for (int t = 0; t < 64; ++t) {
    const u16* Ab = lds4[t & 3][0];
    const u16* Bb = lds4[t & 3][1];
    int tt = (t + 3) & 63;   // wraps at the end -> redundant re-stage, uniform code
    int sb = tt & 3;

    // ---- phase A: B frags + A mf0-3; stage A-chunks of tile tt ----
    s16x8 bfr[4], af[4];
#pragma unroll
    for (int nf = 0; nf < 4; ++nf) bfr[nf] = *(const s16x8*)(Bb + boff + nf * 512);
#pragma unroll
    for (int mf = 0; mf < 4; ++mf) af[mf] = *(const s16x8*)(Ab + aoff + mf * 512);
    gload16(Agst + tt * 32, &lds4[sb][0][wave * 512]);
    gload16(Agst + HSTRIDE + tt * 32, &lds4[sb][0][4096 + wave * 512]);
    __builtin_amdgcn_s_setprio(1);
#pragma unroll
    for (int mf = 0; mf < 4; ++mf)
#pragma unroll
      for (int nf = 0; nf < 4; ++nf)
        acc[mf][nf] = __builtin_amdgcn_mfma_f32_16x16x32_bf16(af[mf], bfr[nf], acc[mf][nf], 0, 0, 0);
    __builtin_amdgcn_s_setprio(0);
    BAR();

    // ---- phase B: A mf4-7 (B held in regs); stage B-chunks of tile tt ----
#pragma unroll
    for (int mf = 0; mf < 4; ++mf) af[mf] = *(const s16x8*)(Ab + aoff + (mf + 4) * 512);
    gload16(Bgst + tt * 32, &lds4[sb][1][wave * 512]);
    gload16(Bgst + HSTRIDE + tt * 32, &lds4[sb][1][4096 + wave * 512]);
    __builtin_amdgcn_s_setprio(1);
#pragma unroll
    for (int mf = 0; mf < 4; ++mf)
#pragma unroll
      for (int nf = 0; nf < 4; ++nf)
        acc[mf + 4][nf] = __builtin_amdgcn_mfma_f32_16x16x32_bf16(af[mf], bfr[nf], acc[mf + 4][nf], 0, 0, 0);
    __builtin_amdgcn_s_setprio(0);
    VMCNT8();  // tile t+1's chunks (issued 3 tiles ago) landed; t+2,t+3 stay in flight
    BAR();
  }
  VMCNT0();  // drain DMA before workgroup teardown

  // epilogue: q|k -> qk[8192][4096]; v (col>=4096) -> Vt transposed
  int crow0 = mt * 256 + wr * 128 + l4 * 4;
  int ccol0 = nt * 256 + wc * 64 + l15;
#pragma unroll
  for (int mf = 0; mf < 8; ++mf)
#pragma unroll
    for (int nf = 0; nf < 4; ++nf) {
      int col = ccol0 + nf * 16;
      int row0 = crow0 + mf * 16;
      if (col >= 4096) {
        int h = (col - 4096) >> 7, dh = (col - 4096) & 127;
        int b = row0 >> 11, s0 = row0 & 2047;
        u16x4 w;
        w.x = f2bfh(acc[mf][nf][0]); w.y = f2bfh(acc[mf][nf][1]);
        w.z = f2bfh(acc[mf][nf][2]); w.w = f2bfh(acc[mf][nf][3]);
        *(u16x4*)(Vt + ((size_t)((b << 4) + h) * 128 + dh) * 2048 + s0) = w;
      } else {
#pragma unroll
        for (int r = 0; r < 4; ++r)
          qk[(size_t)(row0 + r) * 4096 + col] = f2bfh(acc[mf][nf][r]);
      }
    }
}

// ------------- MFMA flash attention v9 (unchanged from round 12, green) -------------
__global__ __launch_bounds__(512, 4) void attn9_k(const u16* __restrict__ qk,
                                                  const u16* __restrict__ Vt,
                                                  u16* __restrict__ outl) {
  __shared__ u16 Ks[2][64 * 128];
  __shared__ u16 Vs[2][128 * 64];
  __shared__ u16 Ps2[8 * 16 * 64];

  int bid = blockIdx.x;
  int xcd = bid & 7, slot = bid >> 3;
  int bh = xcd * 8 + (slot >> 4), qb = slot & 15;
  int b = bh >> 4, h = bh & 15;
  int tid = threadIdx.x, wave = tid >> 6, lane = tid & 63;
  int l15 = lane & 15, l4 = lane >> 4;
  int q0 = qb * 128 + wave * 16;
  const float ksc = 0.12751743f;

  s16x8 qf[4];
#pragma unroll
  for (int kf = 0; kf < 4; ++kf)
    qf[kf] = *(const s16x8*)(qk + (size_t)(b * 2048 + q0 + l15) * 4096 +
                             h * 128 + kf * 32 + l4 * 8);

  f32x4 po[8];
  float smrun = -1e30f, lrun = 0.f;
#pragma unroll
  for (int n2 = 0; n2 < 8; ++n2) po[n2] = f32x4{0.f, 0.f, 0.f, 0.f};

  char* PsW = (char*)Ps2 + wave * 2048;

  int krow_b = wave * 8;
  int vrow_b = wave * 16;
  int kj = lane & 15;
  int vj = lane & 7;

  s16x8 kr[2], vr[2];
#define GLOAD_TILE(kv0)                                                                  \
  _Pragma("unroll") for (int i = 0; i < 2; ++i) {                                        \
    int row = krow_b + i * 4 + (lane >> 4);                                              \
    kr[i] = *(const s16x8*)(qk + (size_t)(b * 2048 + (kv0) + row) * 4096 + 2048 +        \
                            h * 128 + kj * 8);                                           \
    int row2 = vrow_b + i * 8 + (lane >> 3);                                             \
    vr[i] = *(const s16x8*)(Vt + (size_t)(bh * 128 + row2) * 2048 + (kv0) + vj * 8);     \
  }

  GLOAD_TILE(0)

  for (int t = 0; t < 32; ++t) {
    int cur = t & 1;
    u16* Ksc = Ks[cur];
    u16* Vsc = Vs[cur];
#pragma unroll
    for (int i = 0; i < 2; ++i) {
      int row = krow_b + i * 4 + (lane >> 4);
      *(s16x8*)(Ksc + row * 128 + ((kj ^ (row & 7)) * 8)) = kr[i];
      int row2 = vrow_b + i * 8 + (lane >> 3);
      *(s16x8*)(Vsc + row2 * 64 + ((vj ^ (row2 & 7)) * 8)) = vr[i];
    }
    __syncthreads();
    if (t < 31) GLOAD_TILE((t + 1) * 64)

    f32x4 sa[4];
#pragma unroll
    for (int nf = 0; nf < 4; ++nf) sa[nf] = f32x4{0.f, 0.f, 0.f, 0.f};
    __builtin_amdgcn_s_setprio(1);
#pragma unroll
    for (int kf = 0; kf < 4; ++kf) {
      s16x8 kb[4];
#pragma unroll
      for (int nf = 0; nf < 4; ++nf) {
        int row = nf * 16 + l15;
        int sl = ((kf * 4 + l4) ^ (row & 7)) * 8;
        kb[nf] = *(const s16x8*)(Ksc + row * 128 + sl);
      }
#pragma unroll
      for (int nf = 0; nf < 4; ++nf)
        sa[nf] = __builtin_amdgcn_mfma_f32_16x16x32_bf16(kb[nf], qf[kf], sa[nf], 0, 0, 0);
    }
    __builtin_amdgcn_s_setprio(0);

    {
      float m01 = fmaxf(fmaxf(sa[0][0], sa[0][1]), fmaxf(sa[0][2], sa[0][3]));
      float m23 = fmaxf(fmaxf(sa[1][0], sa[1][1]), fmaxf(sa[1][2], sa[1][3]));
      float m45 = fmaxf(fmaxf(sa[2][0], sa[2][1]), fmaxf(sa[2][2], sa[2][3]));
      float m67 = fmaxf(fmaxf(sa[3][0], sa[3][1]), fmaxf(sa[3][2], sa[3][3]));
      float pmax = fmaxf(fmaxf(m01, m23), fmaxf(m45, m67));
      pmax = fmaxf(pmax, __shfl_xor(pmax, 16, 64));
      pmax = fmaxf(pmax, __shfl_xor(pmax, 32, 64));
      float smax = pmax * ksc;
      if (!__all(smax - smrun <= 8.0f)) {
        float mnew = fmaxf(smrun, smax);
        float fsc = exp2f(smrun - mnew);
        lrun *= fsc;
#pragma unroll
        for (int n2 = 0; n2 < 8; ++n2)
#pragma unroll
          for (int r = 0; r < 4; ++r) po[n2][r] *= fsc;
        smrun = mnew;
      }
      int row = l15;
      int swz = (row & 7) << 4;
      float ssum = 0.f;
#pragma unroll
      for (int nf = 0; nf < 4; ++nf) {
        float p0 = exp2f(fmaf(sa[nf][0], ksc, -smrun));
        float p1 = exp2f(fmaf(sa[nf][1], ksc, -smrun));
        float p2 = exp2f(fmaf(sa[nf][2], ksc, -smrun));
        float p3 = exp2f(fmaf(sa[nf][3], ksc, -smrun));
        ssum += (p0 + p1) + (p2 + p3);
        u16x4 w;
        w.x = f2bfh(p0); w.y = f2bfh(p1); w.z = f2bfh(p2); w.w = f2bfh(p3);
        *(u16x4*)(PsW + row * 128 + (((nf * 4 + l4) * 8) ^ swz)) = w;
      }
      ssum += __shfl_xor(ssum, 16, 64);
      ssum += __shfl_xor(ssum, 32, 64);
      lrun += ssum;
    }

    s16x8 pb[2];
    {
      int row = l15;
      int swz = (row & 7) << 4;
#pragma unroll
      for (int k2 = 0; k2 < 2; ++k2)
        pb[k2] = *(const s16x8*)(PsW + row * 128 + ((k2 * 64 + l4 * 16) ^ swz));
    }

    __builtin_amdgcn_s_setprio(1);
#pragma unroll
    for (int n2 = 0; n2 < 8; ++n2) {
#pragma unroll
      for (int k2 = 0; k2 < 2; ++k2) {
        int row = n2 * 16 + l15;
        int sl = ((k2 * 4 + l4) ^ (row & 7)) * 8;
        s16x8 vb = *(const s16x8*)(Vsc + row * 64 + sl);
        po[n2] = __builtin_amdgcn_mfma_f32_16x16x32_bf16(vb, pb[k2], po[n2], 0, 0, 0);
      }
    }
    __builtin_amdgcn_s_setprio(0);
  }
#undef GLOAD_TILE

  {
    float inv = 1.0f / lrun;
#pragma unroll
    for (int n2 = 0; n2 < 8; ++n2) {
      u16x4 w;
      w.x = f2bfh(po[n2][0] * inv);
      w.y = f2bfh(po[n2][1] * inv);
      w.z = f2bfh(po[n2][2] * inv);
      w.w = f2bfh(po[n2][3] * inv);
      *(u16x4*)(outl + (size_t)(b * 2048 + q0 + l15) * 2048 + h * 128 + n2 * 16 + l4 * 4) = w;
    }
  }
}

extern "C" void kernel_launch(void* const* d_in, const int* in_sizes, int n_in,
                              void* d_out, int out_size, void* d_ws, size_t ws_size,
                              hipStream_t stream) {
  (void)in_sizes; (void)n_in;
  const float* hs  = (const float*)d_in[0];
  const float* Wq  = (const float*)d_in[1];
  const float* Wkd = (const float*)d_in[2];
  const float* Wvd = (const float*)d_in[3];
  const float* Wku = (const float*)d_in[4];
  const float* Wo  = (const float*)d_in[5];
  float* out = (float*)d_out;
  char* ws = (char*)d_ws;

  // ws sentinel: need 192 MiB
  if (ws_size < 201326592ull) {
    fill_k<<<4096, 256, 0, stream>>>(out, out_size, 1e9f);
    return;
  }

  // workspace layout (192 MiB):
  //  [0,        25.17M) W3   (cvtall -> qkv GEMM)
  //  [25.17M,   33.55M) WcH  (Wc GEMM -> final GEMM)
  //  [33.55M,   67.11M) hsB  (cvtall -> qkv GEMM); then outl (attn -> final GEMM)
  //  [67.11M,  134.22M) qk   [8192][4096] bf16 (q|k)
  //  [134.22M, 142.61M) WoB ; [142.61M, 150.99M) WkuT
  //  [167.77M, 201.33M) Vt
  u16* W3   = (u16*)(ws);
  u16* WcH  = (u16*)(ws + 25165824);
  u16* hsB  = (u16*)(ws + 33554432);
  u16* outl = (u16*)(ws + 33554432);
  u16* qk   = (u16*)(ws + 67108864);
  u16* WoB  = (u16*)(ws + 134217728);
  u16* WkuT = (u16*)(ws + 142606336);
  u16* Vt   = (u16*)(ws + 167772160);

  cvtall_k<<<32768, 256, 0, stream>>>(hs, Wq, Wkd, Wvd, Wo, hsB, W3, WoB);
  cvtT_k<<<dim3(64, 64), dim3(32, 8), 0, stream>>>(Wku, WkuT);

  // Wc = Wo @ Wk_up (128^2 m97 structure)
  btgemm_k<u16, 1><<<256, 256, 0, stream>>>(WoB, WkuT, WcH, 2048, 2048, 2048);

  // qkv projections via pipelined 256^2 kernel; v columns routed transposed into Vt
  gemm256qkv_k<<<768, 512, 0, stream>>>(hsB, W3, qk, Vt);

  attn9_k<<<1024, 512, 0, stream>>>(qk, Vt, outl);

  // out = out_lat @ Wc^T  (fp32 out, 128^2 structure)
  btgemm_k<float, 0><<<1024, 256, 0, stream>>>(outl, WcH, out, 8192, 2048, 2048);
}